// Round 1
// baseline (514.468 us; speedup 1.0000x reference)
//
#include <hip/hip_runtime.h>
#include <hip/hip_bf16.h>
#include <cstdint>
#include <cstddef>

#define NB    1024          // batch (graphs)
#define NF    32            // fields per graph
#define DIN   64
#define HID   128
#define HEADS 4
#define NTOT  (NB*NF)       // 32768 nodes
#define H1DIM (HEADS*HID)   // 512

// ---------------------------------------------------------------------------
// Kernel 1: fused aligner GEMV (64->128) + LayerNorm + sigmoid gate
// block = 128 threads (one node per block), grid = NTOT
// ---------------------------------------------------------------------------
__global__ __launch_bounds__(128) void k_align(
    const float* __restrict__ xf, const float* __restrict__ Wa,
    const float* __restrict__ ba, const float* __restrict__ gamma,
    const float* __restrict__ beta, const float* __restrict__ gl,
    float* __restrict__ x0)
{
    int n = blockIdx.x, t = threadIdx.x;
    __shared__ float xr[DIN];
    __shared__ float red[4];
    if (t < DIN) xr[t] = xf[(size_t)n * DIN + t];
    __syncthreads();

    float acc = ba[t];
    #pragma unroll
    for (int k = 0; k < DIN; ++k) acc = fmaf(xr[k], Wa[k * HID + t], acc);

    // block reduce: sum and sum-of-squares over 128 values (2 waves)
    float s = acc, s2 = acc * acc;
    #pragma unroll
    for (int o = 32; o > 0; o >>= 1) { s += __shfl_down(s, o); s2 += __shfl_down(s2, o); }
    int w = t >> 6;
    if ((t & 63) == 0) { red[w] = s; red[2 + w] = s2; }
    __syncthreads();
    float S = red[0] + red[1], S2 = red[2] + red[3];
    float mu  = S * (1.0f / HID);
    float var = S2 * (1.0f / HID) - mu * mu;
    float rs  = rsqrtf(var + 1e-5f);
    float g   = 1.0f / (1.0f + __expf(-gl[n & (NF - 1)]));
    x0[(size_t)n * HID + t] = ((acc - mu) * rs * gamma[t] + beta[t]) * g;
}

// ---------------------------------------------------------------------------
// Tiled SGEMM: C[M,N] = A[M,K] @ B[K,N]; BM=BN=64, BK=32, 256 thr, 4x4 micro
// ---------------------------------------------------------------------------
template<int BM, int BN, int BK>
__global__ __launch_bounds__(256) void sgemm(
    const float* __restrict__ A, const float* __restrict__ B,
    float* __restrict__ C, int M, int N, int K)
{
    __shared__ float As[BK][BM + 4];
    __shared__ float Bs[BK][BN];
    int tid = threadIdx.x;
    int tx = tid & 15, ty = tid >> 4;
    int bm = blockIdx.y * BM, bn = blockIdx.x * BN;
    float acc[4][4] = {};

    for (int k0 = 0; k0 < K; k0 += BK) {
        #pragma unroll
        for (int l = tid; l < BM * BK; l += 256) {
            int i = l / BK, kk = l % BK;
            As[kk][i] = A[(size_t)(bm + i) * K + k0 + kk];
        }
        #pragma unroll
        for (int l = tid; l < BK * BN; l += 256) {
            int kk = l / BN, j = l % BN;
            Bs[kk][j] = B[(size_t)(k0 + kk) * N + bn + j];
        }
        __syncthreads();
        #pragma unroll
        for (int kk = 0; kk < BK; ++kk) {
            float4 av = *(const float4*)&As[kk][ty * 4];
            float4 bv = *(const float4*)&Bs[kk][tx * 4];
            float a[4] = {av.x, av.y, av.z, av.w};
            float b[4] = {bv.x, bv.y, bv.z, bv.w};
            #pragma unroll
            for (int r = 0; r < 4; ++r)
                #pragma unroll
                for (int c = 0; c < 4; ++c)
                    acc[r][c] = fmaf(a[r], b[c], acc[r][c]);
        }
        __syncthreads();
    }
    #pragma unroll
    for (int r = 0; r < 4; ++r) {
        float4 o = {acc[r][0], acc[r][1], acc[r][2], acc[r][3]};
        *(float4*)&C[(size_t)(bm + ty * 4 + r) * N + bn + tx * 4] = o;
    }
}

// ---------------------------------------------------------------------------
// Per-node attention logits, layer1: es[n,h], ed[n,h]; block=256 (4 waves)
// ---------------------------------------------------------------------------
__global__ __launch_bounds__(256) void k_logits1(
    const float* __restrict__ h1, const float* __restrict__ as1,
    const float* __restrict__ ad1, float* __restrict__ es, float* __restrict__ ed)
{
    int n = blockIdx.x;
    int h = threadIdx.x >> 6, lane = threadIdx.x & 63;
    const float* hr = h1 + (size_t)n * H1DIM + h * HID;
    float ps = 0.f, pd = 0.f;
    #pragma unroll
    for (int f = lane; f < HID; f += 64) {
        float v = hr[f];
        ps = fmaf(v, as1[h * HID + f], ps);
        pd = fmaf(v, ad1[h * HID + f], pd);
    }
    #pragma unroll
    for (int o = 32; o > 0; o >>= 1) { ps += __shfl_down(ps, o); pd += __shfl_down(pd, o); }
    if (lane == 0) { es[n * HEADS + h] = ps; ed[n * HEADS + h] = pd; }
}

// layer2 (1 head): block = 64
__global__ __launch_bounds__(64) void k_logits2(
    const float* __restrict__ h2, const float* __restrict__ as2,
    const float* __restrict__ ad2, float* __restrict__ es, float* __restrict__ ed)
{
    int n = blockIdx.x, lane = threadIdx.x;
    const float* hr = h2 + (size_t)n * HID;
    float ps = 0.f, pd = 0.f;
    #pragma unroll
    for (int f = lane; f < HID; f += 64) {
        float v = hr[f];
        ps = fmaf(v, as2[f], ps);
        pd = fmaf(v, ad2[f], pd);
    }
    #pragma unroll
    for (int o = 32; o > 0; o >>= 1) { ps += __shfl_down(ps, o); pd += __shfl_down(pd, o); }
    if (lane == 0) { es[n] = ps; ed[n] = pd; }
}

// ---------------------------------------------------------------------------
// CSR build (by destination)
// ---------------------------------------------------------------------------
__global__ void k_deg(const int* __restrict__ dst, int E, int* __restrict__ deg)
{
    int e = blockIdx.x * blockDim.x + threadIdx.x;
    if (e < E) atomicAdd(&deg[dst[e]], 1);
}

// single block 1024 threads: exclusive scan of deg[NTOT] -> off, cursor
__global__ __launch_bounds__(1024) void k_scan(
    const int* __restrict__ deg, int* __restrict__ off,
    int* __restrict__ cursor, int Nn)
{
    __shared__ int ss[1024];
    int t = threadIdx.x;
    int base = t * 32;
    int loc[32];
    int s = 0;
    #pragma unroll
    for (int i = 0; i < 32; ++i) { loc[i] = s; s += deg[base + i]; }
    int tot = s;
    ss[t] = s;
    __syncthreads();
    for (int o = 1; o < 1024; o <<= 1) {
        int v = (t >= o) ? ss[t - o] : 0;
        __syncthreads();
        ss[t] += v;
        __syncthreads();
    }
    int pre = ss[t] - tot;
    #pragma unroll
    for (int i = 0; i < 32; ++i) {
        int v = pre + loc[i];
        off[base + i] = v;
        cursor[base + i] = v;
    }
    if (t == 1023) off[Nn] = pre + tot;
}

__global__ void k_scatter(const int* __restrict__ src, const int* __restrict__ dst,
                          int E, int* __restrict__ cursor, int* __restrict__ esrc)
{
    int e = blockIdx.x * blockDim.x + threadIdx.x;
    if (e < E) {
        int p = atomicAdd(&cursor[dst[e]], 1);
        esrc[p] = src[e];
    }
}

// ---------------------------------------------------------------------------
// GAT layer-1 softmax + aggregate + bias + ELU. block=128, grid=NTOT
// ---------------------------------------------------------------------------
__global__ __launch_bounds__(128) void k_gat1_agg(
    const float* __restrict__ h1, const float* __restrict__ es,
    const float* __restrict__ ed, const int* __restrict__ off,
    const int* __restrict__ esrc, const float* __restrict__ b1,
    float* __restrict__ x1)
{
    int n = blockIdx.x, t = threadIdx.x;
    int s0 = off[n], s1 = off[n + 1];
    float edh[HEADS];
    #pragma unroll
    for (int h = 0; h < HEADS; ++h) edh[h] = ed[n * HEADS + h];

    float mx[HEADS] = {-INFINITY, -INFINITY, -INFINITY, -INFINITY};
    for (int j = s0; j < s1; ++j) {
        int s = esrc[j];
        #pragma unroll
        for (int h = 0; h < HEADS; ++h) {
            float l = es[s * HEADS + h] + edh[h];
            l = fmaxf(l, 0.2f * l);
            mx[h] = fmaxf(mx[h], l);
        }
    }
    float sum[HEADS] = {0.f, 0.f, 0.f, 0.f};
    float acc[HEADS] = {0.f, 0.f, 0.f, 0.f};
    for (int j = s0; j < s1; ++j) {
        int s = esrc[j];
        const float* hr = h1 + (size_t)s * H1DIM;
        #pragma unroll
        for (int h = 0; h < HEADS; ++h) {
            float l = es[s * HEADS + h] + edh[h];
            l = fmaxf(l, 0.2f * l);
            float ex = __expf(l - mx[h]);
            sum[h] += ex;
            acc[h] = fmaf(ex, hr[h * HID + t], acc[h]);
        }
    }
    #pragma unroll
    for (int h = 0; h < HEADS; ++h) {
        float v = acc[h] / sum[h] + b1[h * HID + t];
        x1[(size_t)n * H1DIM + h * HID + t] = (v > 0.f) ? v : expm1f(v);
    }
}

// ---------------------------------------------------------------------------
// GAT layer-2 softmax + aggregate + bias, fused with mean-pool atomics
// ---------------------------------------------------------------------------
__global__ __launch_bounds__(128) void k_gat2_pool(
    const float* __restrict__ h2, const float* __restrict__ es,
    const float* __restrict__ ed, const int* __restrict__ off,
    const int* __restrict__ esrc, const float* __restrict__ b2,
    const int* __restrict__ bidx, float* __restrict__ dout,
    float* __restrict__ counts)
{
    int n = blockIdx.x, t = threadIdx.x;
    int s0 = off[n], s1 = off[n + 1];
    float edn = ed[n];
    float mx = -INFINITY;
    for (int j = s0; j < s1; ++j) {
        float l = es[esrc[j]] + edn;
        l = fmaxf(l, 0.2f * l);
        mx = fmaxf(mx, l);
    }
    float sum = 0.f, acc = 0.f;
    for (int j = s0; j < s1; ++j) {
        int s = esrc[j];
        float l = es[s] + edn;
        l = fmaxf(l, 0.2f * l);
        float ex = __expf(l - mx);
        sum += ex;
        acc = fmaf(ex, h2[(size_t)s * HID + t], acc);
    }
    float val = acc / sum + b2[t];
    int b = bidx[n];
    atomicAdd(&dout[(size_t)b * HID + t], val);
    if (t == 0) atomicAdd(&counts[b], 1.0f);
}

// divide by counts + write gate
__global__ __launch_bounds__(128) void k_final(
    float* __restrict__ dout, const float* __restrict__ counts,
    const float* __restrict__ gl)
{
    int i = blockIdx.x * blockDim.x + threadIdx.x;   // 0 .. NB*HID-1
    dout[i] /= counts[i >> 7];
    if (blockIdx.x == 0 && threadIdx.x < NF)
        dout[NB * HID + threadIdx.x] = 1.0f / (1.0f + __expf(-gl[threadIdx.x]));
}

// ---------------------------------------------------------------------------
extern "C" void kernel_launch(void* const* d_in, const int* in_sizes, int n_in,
                              void* d_out, int out_size, void* d_ws, size_t ws_size,
                              hipStream_t stream)
{
    const float* xf    = (const float*)d_in[0];
    const float* Wa    = (const float*)d_in[1];
    const float* ba    = (const float*)d_in[2];
    const float* gamma = (const float*)d_in[3];
    const float* beta  = (const float*)d_in[4];
    const float* gl    = (const float*)d_in[5];
    const float* w1    = (const float*)d_in[6];
    const float* as1   = (const float*)d_in[7];
    const float* ad1   = (const float*)d_in[8];
    const float* b1    = (const float*)d_in[9];
    const float* w2    = (const float*)d_in[10];
    const float* as2   = (const float*)d_in[11];
    const float* ad2   = (const float*)d_in[12];
    const float* b2    = (const float*)d_in[13];
    const int*   eidx  = (const int*)d_in[14];
    const int*   bidx  = (const int*)d_in[15];
    const int E = in_sizes[14] / 2;
    const int* srcG = eidx;
    const int* dstG = eidx + E;

    // workspace carve-up (all region sizes are multiples of 256 B)
    char* w = (char*)d_ws;
    float* h1   = (float*)w; w += (size_t)NTOT * H1DIM * 4;   // 64 MB
    float* x1   = (float*)w; w += (size_t)NTOT * H1DIM * 4;   // 64 MB
    float* x0   = (float*)w;                                   // shared: x0 then h2
    float* h2   = x0;        w += (size_t)NTOT * HID * 4;      // 16 MB
    float* es1  = (float*)w; w += (size_t)NTOT * HEADS * 4;
    float* ed1  = (float*)w; w += (size_t)NTOT * HEADS * 4;
    float* es2  = (float*)w; w += (size_t)NTOT * 4;
    float* ed2  = (float*)w; w += (size_t)NTOT * 4;
    int*   deg  = (int*)w;   w += (size_t)NTOT * 4;
    int*   offs = (int*)w;   w += (size_t)(NTOT + 64) * 4;
    int*   curs = (int*)w;   w += (size_t)NTOT * 4;
    int*   esrc = (int*)w;   w += (size_t)E * 4;
    float* cnts = (float*)w; w += (size_t)NB * 4;

    hipMemsetAsync(deg, 0, NTOT * sizeof(int), stream);
    hipMemsetAsync(d_out, 0, (size_t)out_size * sizeof(float), stream);
    hipMemsetAsync(cnts, 0, NB * sizeof(float), stream);

    // 1. aligner + LN + gate
    k_align<<<NTOT, 128, 0, stream>>>(xf, Wa, ba, gamma, beta, gl, x0);

    // 2. CSR build
    int eb = (E + 255) / 256;
    k_deg<<<eb, 256, 0, stream>>>(dstG, E, deg);
    k_scan<<<1, 1024, 0, stream>>>(deg, offs, curs, NTOT);
    k_scatter<<<eb, 256, 0, stream>>>(srcG, dstG, E, curs, esrc);

    // 3. h1 = x0 @ w1  [32768,128]@[128,512]
    sgemm<64, 64, 32><<<dim3(H1DIM / 64, NTOT / 64), 256, 0, stream>>>(
        x0, w1, h1, NTOT, H1DIM, HID);

    // 4. per-node logits, layer 1
    k_logits1<<<NTOT, 256, 0, stream>>>(h1, as1, ad1, es1, ed1);

    // 5. GAT1 aggregate + bias + ELU -> x1 [32768,512]
    k_gat1_agg<<<NTOT, 128, 0, stream>>>(h1, es1, ed1, offs, esrc, b1, x1);

    // 6. h2 = x1 @ w2  [32768,512]@[512,128]
    sgemm<64, 64, 32><<<dim3(HID / 64, NTOT / 64), 256, 0, stream>>>(
        x1, w2, h2, NTOT, HID, H1DIM);

    // 7. per-node logits, layer 2
    k_logits2<<<NTOT, 64, 0, stream>>>(h2, as2, ad2, es2, ed2);

    // 8. GAT2 aggregate + bias, fused mean-pool accumulation
    k_gat2_pool<<<NTOT, 128, 0, stream>>>(h2, es2, ed2, offs, esrc, b2, bidx,
                                          (float*)d_out, cnts);

    // 9. divide + gate output
    k_final<<<NB, 128, 0, stream>>>((float*)d_out, cnts, gl);
}

// Round 2
// 239.288 us; speedup vs baseline: 2.1500x; 2.1500x over previous
//
#include <hip/hip_runtime.h>
#include <hip/hip_bf16.h>
#include <cstdint>
#include <cstddef>

#define NB    1024          // batch (graphs)
#define NF    32            // fields per graph
#define DIN   64
#define HID   128
#define HEADS 4
#define NTOT  (NB*NF)       // 32768 nodes
#define H1DIM (HEADS*HID)   // 512

typedef __attribute__((ext_vector_type(8))) short          bf16x8;
typedef __attribute__((ext_vector_type(8))) unsigned short u16x8;
typedef __attribute__((ext_vector_type(4))) float          f32x4;

__device__ __forceinline__ float bf2f(unsigned short u) {
    return __uint_as_float(((unsigned)u) << 16);
}
__device__ __forceinline__ unsigned short f2bf(float f) {
    unsigned u = __float_as_uint(f);
    return (unsigned short)((u + 0x7FFF + ((u >> 16) & 1)) >> 16);   // RNE
}

// ---------------------------------------------------------------------------
// fused aligner GEMV (64->128) + LayerNorm + sigmoid gate -> x0 (bf16)
// ---------------------------------------------------------------------------
__global__ __launch_bounds__(128) void k_align(
    const float* __restrict__ xf, const float* __restrict__ Wa,
    const float* __restrict__ ba, const float* __restrict__ gamma,
    const float* __restrict__ beta, const float* __restrict__ gl,
    unsigned short* __restrict__ x0b)
{
    int n = blockIdx.x, t = threadIdx.x;
    __shared__ float xr[DIN];
    __shared__ float red[4];
    if (t < DIN) xr[t] = xf[(size_t)n * DIN + t];
    __syncthreads();

    float acc = ba[t];
    #pragma unroll
    for (int k = 0; k < DIN; ++k) acc = fmaf(xr[k], Wa[k * HID + t], acc);

    float s = acc, s2 = acc * acc;
    #pragma unroll
    for (int o = 32; o > 0; o >>= 1) { s += __shfl_down(s, o); s2 += __shfl_down(s2, o); }
    int w = t >> 6;
    if ((t & 63) == 0) { red[w] = s; red[2 + w] = s2; }
    __syncthreads();
    float S = red[0] + red[1], S2 = red[2] + red[3];
    float mu  = S * (1.0f / HID);
    float var = S2 * (1.0f / HID) - mu * mu;
    float rs  = rsqrtf(var + 1e-5f);
    float g   = 1.0f / (1.0f + __expf(-gl[n & (NF - 1)]));
    float v   = ((acc - mu) * rs * gamma[t] + beta[t]) * g;
    x0b[(size_t)n * HID + t] = f2bf(v);
}

// ---------------------------------------------------------------------------
// cast + transpose weights to bf16 B^T layout: w1T[512][128], w2T[128][512]
// ---------------------------------------------------------------------------
__global__ __launch_bounds__(256) void k_prep(
    const float* __restrict__ w1, const float* __restrict__ w2,
    unsigned short* __restrict__ w1T, unsigned short* __restrict__ w2T)
{
    int i = blockIdx.x * 256 + threadIdx.x;
    if (i < HID * H1DIM) {                 // w1T[n][k] = w1[k][n]
        int n = i >> 7, k = i & 127;
        w1T[i] = f2bf(w1[k * H1DIM + n]);
    } else {
        int j = i - HID * H1DIM;           // w2T[n][k] = w2[k][n]
        int n = j >> 9, k = j & 511;
        w2T[j] = f2bf(w2[k * HID + n]);
    }
}

// ---------------------------------------------------------------------------
// per-graph edge multiplicity count matrix cnt[b][dl][sl]
// ---------------------------------------------------------------------------
__global__ void k_cnt(const int* __restrict__ src, const int* __restrict__ dst,
                      const int* __restrict__ bidx, int E, int* __restrict__ cnt)
{
    int e = blockIdx.x * 256 + threadIdx.x;
    if (e >= E) return;
    int d = dst[e], s = src[e];
    int b = bidx[d];
    atomicAdd(&cnt[b * (NF * NF) + (d - b * NF) * NF + (s - b * NF)], 1);
}

// ---------------------------------------------------------------------------
// MFMA bf16 GEMM, B pre-transposed: C[M,N] = A[M,K] @ BT[N,K]^T
// BN=128, BK=32, 256 thr = 4 waves in 2x2; wave tile (FM*16) x 64
// ---------------------------------------------------------------------------
template<int BM, int FM, int OUTBF>
__global__ __launch_bounds__(256) void mfma_gemm_bt(
    const unsigned short* __restrict__ A, const unsigned short* __restrict__ BT,
    void* __restrict__ C, int M, int N, int K)
{
    constexpr int LDT = 40;                          // 32 + 8 pad (bf16 elems)
    __shared__ unsigned short As[BM * LDT];
    __shared__ unsigned short Bs[128 * LDT];
    int tid = threadIdx.x, l = tid & 63, w = tid >> 6;
    int wr = w >> 1, wc = w & 1;
    int bm = blockIdx.y * BM, bn = blockIdx.x * 128;

    f32x4 acc[FM][4];
    #pragma unroll
    for (int m = 0; m < FM; ++m)
        #pragma unroll
        for (int n = 0; n < 4; ++n) acc[m][n] = (f32x4){0.f, 0.f, 0.f, 0.f};

    for (int k0 = 0; k0 < K; k0 += 32) {
        for (int i = tid; i < BM * 4; i += 256) {
            int r = i >> 2, ch = i & 3;
            *(u16x8*)&As[r * LDT + ch * 8] =
                *(const u16x8*)&A[(size_t)(bm + r) * K + k0 + ch * 8];
        }
        for (int i = tid; i < 128 * 4; i += 256) {
            int r = i >> 2, ch = i & 3;
            *(u16x8*)&Bs[r * LDT + ch * 8] =
                *(const u16x8*)&BT[(size_t)(bn + r) * K + k0 + ch * 8];
        }
        __syncthreads();
        bf16x8 af[FM], bfr[4];
        #pragma unroll
        for (int m = 0; m < FM; ++m)
            af[m] = *(const bf16x8*)&As[(wr * FM * 16 + m * 16 + (l & 15)) * LDT + (l >> 4) * 8];
        #pragma unroll
        for (int n = 0; n < 4; ++n)
            bfr[n] = *(const bf16x8*)&Bs[(wc * 64 + n * 16 + (l & 15)) * LDT + (l >> 4) * 8];
        #pragma unroll
        for (int m = 0; m < FM; ++m)
            #pragma unroll
            for (int n = 0; n < 4; ++n)
                acc[m][n] = __builtin_amdgcn_mfma_f32_16x16x32_bf16(af[m], bfr[n], acc[m][n], 0, 0, 0);
        __syncthreads();
    }

    int r0 = bm + wr * FM * 16 + (l >> 4) * 4;
    int c0 = bn + wc * 64 + (l & 15);
    #pragma unroll
    for (int m = 0; m < FM; ++m)
        #pragma unroll
        for (int n = 0; n < 4; ++n)
            #pragma unroll
            for (int v = 0; v < 4; ++v) {
                size_t idx = (size_t)(r0 + m * 16 + v) * N + (c0 + n * 16);
                if (OUTBF) ((unsigned short*)C)[idx] = f2bf(acc[m][n][v]);
                else       ((float*)C)[idx] = acc[m][n][v];
            }
}

// ---------------------------------------------------------------------------
// logits layer1 from bf16 h1: wave per node, 4 heads via 16-lane groups
// ---------------------------------------------------------------------------
__global__ __launch_bounds__(256) void k_logits1(
    const unsigned short* __restrict__ h1, const float* __restrict__ as1,
    const float* __restrict__ ad1, float* __restrict__ es, float* __restrict__ ed)
{
    int w = threadIdx.x >> 6, l = threadIdx.x & 63;
    int n = blockIdx.x * 4 + w;
    u16x8 u = *(const u16x8*)&h1[(size_t)n * H1DIM + l * 8];
    int h = l >> 4, fb = h * HID + (l & 15) * 8;
    float ps = 0.f, pd = 0.f;
    #pragma unroll
    for (int j = 0; j < 8; ++j) {
        float v = bf2f((unsigned short)u[j]);
        ps = fmaf(v, as1[fb + j], ps);
        pd = fmaf(v, ad1[fb + j], pd);
    }
    #pragma unroll
    for (int o = 1; o < 16; o <<= 1) { ps += __shfl_xor(ps, o); pd += __shfl_xor(pd, o); }
    if ((l & 15) == 0) { es[n * HEADS + h] = ps; ed[n * HEADS + h] = pd; }
}

// logits layer2 from fp32 h2: wave per node
__global__ __launch_bounds__(256) void k_logits2(
    const float* __restrict__ h2, const float* __restrict__ as2,
    const float* __restrict__ ad2, float* __restrict__ es, float* __restrict__ ed)
{
    int w = threadIdx.x >> 6, l = threadIdx.x & 63;
    int n = blockIdx.x * 4 + w;
    float2 v = *(const float2*)&h2[(size_t)n * HID + l * 2];
    float ps = v.x * as2[l * 2] + v.y * as2[l * 2 + 1];
    float pd = v.x * ad2[l * 2] + v.y * ad2[l * 2 + 1];
    #pragma unroll
    for (int o = 1; o < 64; o <<= 1) { ps += __shfl_xor(ps, o); pd += __shfl_xor(pd, o); }
    if (l == 0) { es[n] = ps; ed[n] = pd; }
}

// ---------------------------------------------------------------------------
// dense per-graph GAT1: softmax(count-weighted) + aggregate + bias + ELU
// block = 256 thr, one graph; h1 slice staged in LDS (bf16, 32 KB)
// ---------------------------------------------------------------------------
#define ALP (NF*NF + 8)     // per-head alpha stride, padded (bank spread)

__global__ __launch_bounds__(256) void k_gat1_dense(
    const unsigned short* __restrict__ h1, const float* __restrict__ es,
    const float* __restrict__ ed, const int* __restrict__ cnt,
    const float* __restrict__ b1, unsigned short* __restrict__ x1)
{
    int b = blockIdx.x, t = threadIdx.x;
    int nb = b * NF;
    __shared__ unsigned short h1s[NF * H1DIM];          // 32 KB
    __shared__ float alphaL[HEADS * ALP];               // ~16.5 KB
    __shared__ unsigned char cntL[NF * NF];             // 1 KB
    __shared__ float esL[NF * HEADS], edL[NF * HEADS];  // 1 KB

    const u16x8* gsrc = (const u16x8*)(h1 + (size_t)nb * H1DIM);
    u16x8* ldst = (u16x8*)h1s;
    for (int i = t; i < NF * H1DIM / 8; i += 256) ldst[i] = gsrc[i];
    for (int i = t; i < NF * NF; i += 256) cntL[i] = (unsigned char)cnt[b * NF * NF + i];
    if (t < NF * HEADS) { esL[t] = es[nb * HEADS + t]; edL[t] = ed[nb * HEADS + t]; }
    __syncthreads();

    if (t < NF * HEADS) {                     // (d,h) per thread
        int d = t >> 2, h = t & 3;
        float edv = edL[d * HEADS + h];
        float mx = -INFINITY;
        #pragma unroll
        for (int s = 0; s < NF; ++s) {
            if (cntL[d * NF + s]) {
                float lg = esL[s * HEADS + h] + edv;
                lg = fmaxf(lg, 0.2f * lg);
                mx = fmaxf(mx, lg);
            }
        }
        float sum = 0.f;
        #pragma unroll
        for (int s = 0; s < NF; ++s) {
            int c = cntL[d * NF + s];
            float a = 0.f;
            if (c) {
                float lg = esL[s * HEADS + h] + edv;
                lg = fmaxf(lg, 0.2f * lg);
                a = (float)c * __expf(lg - mx);
                sum += a;
            }
            alphaL[h * ALP + d * NF + s] = a;
        }
        float rs = 1.f / sum;
        #pragma unroll
        for (int s = 0; s < NF; ++s) alphaL[h * ALP + d * NF + s] *= rs;
    }
    __syncthreads();

    // aggregation: thread = (d-group of 8) x (8-col group); 8x8 accumulators
    int dg = t >> 6;                 // 0..3 -> rows d = dg*8 .. dg*8+7
    int cg = t & 63;                 // col group: c0 = cg*8
    int c0 = cg * 8;
    int h  = c0 >> 7;
    const float* al = &alphaL[h * ALP];
    float bias[8];
    #pragma unroll
    for (int j = 0; j < 8; ++j) bias[j] = b1[c0 + j];

    float acc[8][8];
    #pragma unroll
    for (int dd = 0; dd < 8; ++dd)
        #pragma unroll
        for (int j = 0; j < 8; ++j) acc[dd][j] = 0.f;

    for (int s = 0; s < NF; ++s) {
        u16x8 u = *(const u16x8*)&h1s[s * H1DIM + c0];
        float hv[8];
        #pragma unroll
        for (int j = 0; j < 8; ++j) hv[j] = bf2f((unsigned short)u[j]);
        #pragma unroll
        for (int dd = 0; dd < 8; ++dd) {
            float a = al[(dg * 8 + dd) * NF + s];
            #pragma unroll
            for (int j = 0; j < 8; ++j) acc[dd][j] = fmaf(a, hv[j], acc[dd][j]);
        }
    }
    #pragma unroll
    for (int dd = 0; dd < 8; ++dd) {
        u16x8 o;
        #pragma unroll
        for (int j = 0; j < 8; ++j) {
            float v = acc[dd][j] + bias[j];
            v = (v > 0.f) ? v : expm1f(v);
            o[j] = (short)f2bf(v);
        }
        *(u16x8*)&x1[(size_t)(nb + dg * 8 + dd) * H1DIM + c0] = o;
    }
}

// ---------------------------------------------------------------------------
// dense per-graph GAT2 + fused mean-pool (collapses to one weighted sum)
// ---------------------------------------------------------------------------
__global__ __launch_bounds__(128) void k_gat2_dense(
    const float* __restrict__ h2, const float* __restrict__ es,
    const float* __restrict__ ed, const int* __restrict__ cnt,
    const float* __restrict__ b2, const float* __restrict__ gl,
    float* __restrict__ dout)
{
    int b = blockIdx.x, t = threadIdx.x;
    int nb = b * NF;
    __shared__ float h2s[NF * HID];          // 16 KB
    __shared__ float alphaL[NF * NF];        // 4 KB
    __shared__ unsigned char cntL[NF * NF];
    __shared__ float esL[NF], edL[NF], wL[NF];

    const float4* gsrc = (const float4*)(h2 + (size_t)nb * HID);
    float4* ld = (float4*)h2s;
    for (int i = t; i < NF * HID / 4; i += 128) ld[i] = gsrc[i];
    for (int i = t; i < NF * NF; i += 128) cntL[i] = (unsigned char)cnt[b * NF * NF + i];
    if (t < NF) { esL[t] = es[nb + t]; edL[t] = ed[nb + t]; }
    __syncthreads();

    if (t < NF) {
        int d = t;
        float edv = edL[d];
        float mx = -INFINITY;
        #pragma unroll
        for (int s = 0; s < NF; ++s) {
            if (cntL[d * NF + s]) {
                float lg = esL[s] + edv;
                lg = fmaxf(lg, 0.2f * lg);
                mx = fmaxf(mx, lg);
            }
        }
        float sum = 0.f;
        #pragma unroll
        for (int s = 0; s < NF; ++s) {
            int c = cntL[d * NF + s];
            float a = 0.f;
            if (c) {
                float lg = esL[s] + edv;
                lg = fmaxf(lg, 0.2f * lg);
                a = (float)c * __expf(lg - mx);
                sum += a;
            }
            alphaL[d * NF + s] = a;
        }
        float rs = 1.f / sum;
        #pragma unroll
        for (int s = 0; s < NF; ++s) alphaL[d * NF + s] *= rs;
    }
    __syncthreads();
    if (t < NF) {                            // w[s] = sum_d alpha[d][s]
        float a = 0.f;
        #pragma unroll
        for (int d = 0; d < NF; ++d) a += alphaL[d * NF + t];
        wL[t] = a;
    }
    __syncthreads();

    float acc = 0.f;
    #pragma unroll 8
    for (int s = 0; s < NF; ++s) acc = fmaf(wL[s], h2s[s * HID + t], acc);
    dout[(size_t)b * HID + t] = acc * (1.0f / NF) + b2[t];
    if (b == 0 && t < NF)
        dout[(size_t)NB * HID + t] = 1.0f / (1.0f + __expf(-gl[t]));
}

// ---------------------------------------------------------------------------
extern "C" void kernel_launch(void* const* d_in, const int* in_sizes, int n_in,
                              void* d_out, int out_size, void* d_ws, size_t ws_size,
                              hipStream_t stream)
{
    const float* xf    = (const float*)d_in[0];
    const float* Wa    = (const float*)d_in[1];
    const float* ba    = (const float*)d_in[2];
    const float* gamma = (const float*)d_in[3];
    const float* beta  = (const float*)d_in[4];
    const float* gl    = (const float*)d_in[5];
    const float* w1    = (const float*)d_in[6];
    const float* as1   = (const float*)d_in[7];
    const float* ad1   = (const float*)d_in[8];
    const float* b1    = (const float*)d_in[9];
    const float* w2    = (const float*)d_in[10];
    const float* as2   = (const float*)d_in[11];
    const float* ad2   = (const float*)d_in[12];
    const float* b2    = (const float*)d_in[13];
    const int*   eidx  = (const int*)d_in[14];
    const int*   bidx  = (const int*)d_in[15];
    const int E = in_sizes[14] / 2;
    const int* srcG = eidx;
    const int* dstG = eidx + E;

    char* w = (char*)d_ws;
    unsigned short* x0b = (unsigned short*)w; w += (size_t)NTOT * HID * 2;     // 8 MB
    unsigned short* h1b = (unsigned short*)w; w += (size_t)NTOT * H1DIM * 2;   // 32 MB
    unsigned short* x1b = (unsigned short*)w; w += (size_t)NTOT * H1DIM * 2;   // 32 MB
    float* h2           = (float*)w;          w += (size_t)NTOT * HID * 4;     // 16 MB
    unsigned short* w1T = (unsigned short*)w; w += (size_t)H1DIM * HID * 2;
    unsigned short* w2T = (unsigned short*)w; w += (size_t)HID * H1DIM * 2;
    float* es1          = (float*)w;          w += (size_t)NTOT * HEADS * 4;
    float* ed1          = (float*)w;          w += (size_t)NTOT * HEADS * 4;
    float* es2          = (float*)w;          w += (size_t)NTOT * 4;
    float* ed2          = (float*)w;          w += (size_t)NTOT * 4;
    int*   cnt          = (int*)w;            w += (size_t)NB * NF * NF * 4;   // 4 MB

    hipMemsetAsync(cnt, 0, (size_t)NB * NF * NF * 4, stream);

    k_prep<<<(2 * HID * H1DIM) / 256, 256, 0, stream>>>(w1, w2, w1T, w2T);
    k_align<<<NTOT, 128, 0, stream>>>(xf, Wa, ba, gamma, beta, gl, x0b);
    k_cnt<<<(E + 255) / 256, 256, 0, stream>>>(srcG, dstG, bidx, E, cnt);

    // h1 = x0 @ w1 : [32768,128] @ [128,512] (bf16 MFMA)
    mfma_gemm_bt<128, 4, 1><<<dim3(H1DIM / 128, NTOT / 128), 256, 0, stream>>>(
        x0b, w1T, h1b, NTOT, H1DIM, HID);

    k_logits1<<<NTOT / 4, 256, 0, stream>>>(h1b, as1, ad1, es1, ed1);
    k_gat1_dense<<<NB, 256, 0, stream>>>(h1b, es1, ed1, cnt, b1, x1b);

    // h2 = x1 @ w2 : [32768,512] @ [512,128] (bf16 MFMA, fp32 out)
    mfma_gemm_bt<64, 2, 0><<<dim3(HID / 128, NTOT / 64), 256, 0, stream>>>(
        x1b, w2T, h2, NTOT, HID, H1DIM);

    k_logits2<<<NTOT / 4, 256, 0, stream>>>(h2, as2, ad2, es2, ed2);
    k_gat2_dense<<<NB, 128, 0, stream>>>(h2, es2, ed2, cnt, b2, gl, (float*)d_out);
}

// Round 4
// 215.299 us; speedup vs baseline: 2.3896x; 1.1114x over previous
//
#include <hip/hip_runtime.h>
#include <hip/hip_bf16.h>
#include <cstdint>
#include <cstddef>

#define NB    1024          // batch (graphs)
#define NF    32            // fields per graph
#define DIN   64
#define HID   128
#define HEADS 4
#define NTOT  (NB*NF)       // 32768 nodes
#define H1DIM (HEADS*HID)   // 512

typedef __attribute__((ext_vector_type(8))) short          bf16x8;
typedef __attribute__((ext_vector_type(8))) unsigned short u16x8;
typedef __attribute__((ext_vector_type(4))) float          f32x4;

__device__ __forceinline__ float bf2f(unsigned short u) {
    return __uint_as_float(((unsigned)u) << 16);
}
__device__ __forceinline__ unsigned short f2bf(float f) {
    unsigned u = __float_as_uint(f);
    return (unsigned short)((u + 0x7FFF + ((u >> 16) & 1)) >> 16);   // RNE
}

// ---------------------------------------------------------------------------
// weight prep: w1T[512][128], w2T[128][512], WaT[128][64]  (all bf16, B^T)
// ---------------------------------------------------------------------------
__global__ __launch_bounds__(256) void k_prep(
    const float* __restrict__ w1, const float* __restrict__ w2,
    const float* __restrict__ Wa,
    unsigned short* __restrict__ w1T, unsigned short* __restrict__ w2T,
    unsigned short* __restrict__ WaT)
{
    int i = blockIdx.x * 256 + threadIdx.x;
    if (i < HID * H1DIM) {                   // w1T[n][k] = w1[k][n]
        int n = i >> 7, k = i & 127;
        w1T[i] = f2bf(w1[k * H1DIM + n]);
    } else if (i < 2 * HID * H1DIM) {        // w2T[n][k] = w2[k][n]
        int j = i - HID * H1DIM;
        int n = j >> 9, k = j & 511;
        w2T[j] = f2bf(w2[k * HID + n]);
    } else {                                 // WaT[c][k] = Wa[k][c]
        int j = i - 2 * HID * H1DIM;
        int c = j >> 6, k = j & 63;
        WaT[j] = f2bf(Wa[k * HID + c]);
    }
}

// ---------------------------------------------------------------------------
// fused aligner: MFMA GEMM (32 rows x 128 cols, K=64) + bias + LN + gate
// block 256 thr (4 waves, 2x2), grid NTOT/32
// ---------------------------------------------------------------------------
__global__ __launch_bounds__(256) void k_align(
    const float* __restrict__ xf, const unsigned short* __restrict__ WaT,
    const float* __restrict__ ba, const float* __restrict__ gamma,
    const float* __restrict__ beta, const float* __restrict__ gl,
    unsigned short* __restrict__ x0b)
{
    __shared__ char smem[23296];
    unsigned short* As = (unsigned short*)smem;            // [32][72]
    unsigned short* Ws = (unsigned short*)(smem + 4608);   // [128][72]
    float*          Cs = (float*)smem;                     // [32][132] (reuse)

    int t = threadIdx.x, l = t & 63, w = t >> 6;
    int r0 = blockIdx.x * 32;

    // stage A tile (fp32 -> bf16)
    {
        int r = t >> 3, k0 = (t & 7) * 8;
        float4 a = *(const float4*)&xf[(size_t)(r0 + r) * DIN + k0];
        float4 b = *(const float4*)&xf[(size_t)(r0 + r) * DIN + k0 + 4];
        u16x8 v;
        v[0] = f2bf(a.x); v[1] = f2bf(a.y); v[2] = f2bf(a.z); v[3] = f2bf(a.w);
        v[4] = f2bf(b.x); v[5] = f2bf(b.y); v[6] = f2bf(b.z); v[7] = f2bf(b.w);
        *(u16x8*)&As[r * 72 + k0] = v;
    }
    // stage W tile (already bf16, B^T layout)
    for (int i = t; i < 128 * 8; i += 256) {
        int c = i >> 3, k0 = (i & 7) * 8;
        *(u16x8*)&Ws[c * 72 + k0] = *(const u16x8*)&WaT[c * 64 + k0];
    }
    __syncthreads();

    int wr = w >> 1, wc = w & 1;            // wave rows 16*wr, cols 64*wc
    f32x4 acc[4];
    #pragma unroll
    for (int n = 0; n < 4; ++n) acc[n] = (f32x4){0.f, 0.f, 0.f, 0.f};

    bf16x8 af0 = *(const bf16x8*)&As[(wr * 16 + (l & 15)) * 72 + (l >> 4) * 8];
    bf16x8 af1 = *(const bf16x8*)&As[(wr * 16 + (l & 15)) * 72 + 32 + (l >> 4) * 8];
    #pragma unroll
    for (int n = 0; n < 4; ++n) {
        bf16x8 b0 = *(const bf16x8*)&Ws[(wc * 64 + n * 16 + (l & 15)) * 72 + (l >> 4) * 8];
        bf16x8 b1 = *(const bf16x8*)&Ws[(wc * 64 + n * 16 + (l & 15)) * 72 + 32 + (l >> 4) * 8];
        acc[n] = __builtin_amdgcn_mfma_f32_16x16x32_bf16(af0, b0, acc[n], 0, 0, 0);
        acc[n] = __builtin_amdgcn_mfma_f32_16x16x32_bf16(af1, b1, acc[n], 0, 0, 0);
    }
    __syncthreads();
    #pragma unroll
    for (int n = 0; n < 4; ++n)
        #pragma unroll
        for (int v = 0; v < 4; ++v)
            Cs[(wr * 16 + (l >> 4) * 4 + v) * 132 + wc * 64 + n * 16 + (l & 15)] = acc[n][v];
    __syncthreads();

    // LN epilogue: thread -> (row = t>>3, 16-col slice p = t&7)
    int row = t >> 3, p = t & 7;
    float vals[16];
    float s = 0.f, s2 = 0.f;
    #pragma unroll
    for (int j = 0; j < 16; ++j) {
        float vv = Cs[row * 132 + p * 16 + j] + ba[p * 16 + j];
        vals[j] = vv; s += vv; s2 += vv * vv;
    }
    #pragma unroll
    for (int o = 1; o < 8; o <<= 1) { s += __shfl_xor(s, o); s2 += __shfl_xor(s2, o); }
    float mu  = s * (1.0f / HID);
    float var = s2 * (1.0f / HID) - mu * mu;
    float rs  = rsqrtf(var + 1e-5f);
    float g   = 1.0f / (1.0f + __expf(-gl[row]));    // (r0+row)&31 == row
    u16x8 o0, o1;
    #pragma unroll
    for (int j = 0; j < 8; ++j) {
        o0[j] = f2bf(((vals[j]     - mu) * rs * gamma[p * 16 + j]     + beta[p * 16 + j])     * g);
        o1[j] = f2bf(((vals[j + 8] - mu) * rs * gamma[p * 16 + j + 8] + beta[p * 16 + j + 8]) * g);
    }
    *(u16x8*)&x0b[(size_t)(r0 + row) * HID + p * 16]     = o0;
    *(u16x8*)&x0b[(size_t)(r0 + row) * HID + p * 16 + 8] = o1;
}

// ---------------------------------------------------------------------------
// per-graph edge multiplicity count matrix cnt[b][dl][sl]
// ---------------------------------------------------------------------------
__global__ void k_cnt(const int* __restrict__ src, const int* __restrict__ dst,
                      const int* __restrict__ bidx, int E, int* __restrict__ cnt)
{
    int e = blockIdx.x * 256 + threadIdx.x;
    if (e >= E) return;
    int d = dst[e], s = src[e];
    int b = bidx[d];
    atomicAdd(&cnt[b * (NF * NF) + (d - b * NF) * NF + (s - b * NF)], 1);
}

// ---------------------------------------------------------------------------
// MFMA bf16 GEMM, B pre-transposed: C[M,N] = A[M,K] @ BT[N,K]^T  (unchanged)
// ---------------------------------------------------------------------------
template<int BM, int FM, int OUTBF>
__global__ __launch_bounds__(256) void mfma_gemm_bt(
    const unsigned short* __restrict__ A, const unsigned short* __restrict__ BT,
    void* __restrict__ C, int M, int N, int K)
{
    constexpr int LDT = 40;
    __shared__ unsigned short As[BM * LDT];
    __shared__ unsigned short Bs[128 * LDT];
    int tid = threadIdx.x, l = tid & 63, w = tid >> 6;
    int wr = w >> 1, wc = w & 1;
    int bm = blockIdx.y * BM, bn = blockIdx.x * 128;

    f32x4 acc[FM][4];
    #pragma unroll
    for (int m = 0; m < FM; ++m)
        #pragma unroll
        for (int n = 0; n < 4; ++n) acc[m][n] = (f32x4){0.f, 0.f, 0.f, 0.f};

    for (int k0 = 0; k0 < K; k0 += 32) {
        for (int i = tid; i < BM * 4; i += 256) {
            int r = i >> 2, ch = i & 3;
            *(u16x8*)&As[r * LDT + ch * 8] =
                *(const u16x8*)&A[(size_t)(bm + r) * K + k0 + ch * 8];
        }
        for (int i = tid; i < 128 * 4; i += 256) {
            int r = i >> 2, ch = i & 3;
            *(u16x8*)&Bs[r * LDT + ch * 8] =
                *(const u16x8*)&BT[(size_t)(bn + r) * K + k0 + ch * 8];
        }
        __syncthreads();
        bf16x8 af[FM], bfr[4];
        #pragma unroll
        for (int m = 0; m < FM; ++m)
            af[m] = *(const bf16x8*)&As[(wr * FM * 16 + m * 16 + (l & 15)) * LDT + (l >> 4) * 8];
        #pragma unroll
        for (int n = 0; n < 4; ++n)
            bfr[n] = *(const bf16x8*)&Bs[(wc * 64 + n * 16 + (l & 15)) * LDT + (l >> 4) * 8];
        #pragma unroll
        for (int m = 0; m < FM; ++m)
            #pragma unroll
            for (int n = 0; n < 4; ++n)
                acc[m][n] = __builtin_amdgcn_mfma_f32_16x16x32_bf16(af[m], bfr[n], acc[m][n], 0, 0, 0);
        __syncthreads();
    }

    int r0 = bm + wr * FM * 16 + (l >> 4) * 4;
    int c0 = bn + wc * 64 + (l & 15);
    #pragma unroll
    for (int m = 0; m < FM; ++m)
        #pragma unroll
        for (int n = 0; n < 4; ++n)
            #pragma unroll
            for (int v = 0; v < 4; ++v) {
                size_t idx = (size_t)(r0 + m * 16 + v) * N + (c0 + n * 16);
                if (OUTBF) ((unsigned short*)C)[idx] = f2bf(acc[m][n][v]);
                else       ((float*)C)[idx] = acc[m][n][v];
            }
}

// ---------------------------------------------------------------------------
// fused GAT1: in-block logits + softmax (unnorm bf16 + 1/sum) + aggregate
// block 256 thr, one graph; NO h1 LDS staging (L1-served global reads)
// ---------------------------------------------------------------------------
#define ALS_D 33
#define ALS_H (NF*ALS_D + 8)     // 1064

__global__ __launch_bounds__(256) void k_gat1f(
    const unsigned short* __restrict__ h1, const float* __restrict__ as1,
    const float* __restrict__ ad1, const int* __restrict__ cnt,
    const float* __restrict__ b1, unsigned short* __restrict__ x1)
{
    int b = blockIdx.x, t = threadIdx.x, nb = b * NF;
    __shared__ float esL[NF * HEADS], edL[NF * HEADS];
    __shared__ unsigned short cntL[NF * NF];
    __shared__ unsigned short aBf[HEADS * ALS_H];
    __shared__ float rsumL[HEADS * NF];

    for (int i = t; i < NF * NF; i += 256)
        cntL[i] = (unsigned short)cnt[b * NF * NF + i];

    // ---- phase A: logits (t -> n = t>>3, h = (t>>1)&3, sd = t&1)
    {
        int n = t >> 3, h = (t >> 1) & 3, sd = t & 1;
        const float* att = sd ? ad1 : as1;
        const unsigned short* hp = h1 + (size_t)(nb + n) * H1DIM + h * HID;
        float p0 = 0.f, p1 = 0.f, p2 = 0.f, p3 = 0.f,
              p4 = 0.f, p5 = 0.f, p6 = 0.f, p7 = 0.f;
        #pragma unroll
        for (int j0 = 0; j0 < HID; j0 += 8) {
            u16x8 u = *(const u16x8*)&hp[j0];
            const float* ap = &att[h * HID + j0];
            p0 = fmaf(bf2f((unsigned short)u[0]), ap[0], p0);
            p1 = fmaf(bf2f((unsigned short)u[1]), ap[1], p1);
            p2 = fmaf(bf2f((unsigned short)u[2]), ap[2], p2);
            p3 = fmaf(bf2f((unsigned short)u[3]), ap[3], p3);
            p4 = fmaf(bf2f((unsigned short)u[4]), ap[4], p4);
            p5 = fmaf(bf2f((unsigned short)u[5]), ap[5], p5);
            p6 = fmaf(bf2f((unsigned short)u[6]), ap[6], p6);
            p7 = fmaf(bf2f((unsigned short)u[7]), ap[7], p7);
        }
        float ps = ((p0 + p1) + (p2 + p3)) + ((p4 + p5) + (p6 + p7));
        if (sd) edL[n * HEADS + h] = ps; else esL[n * HEADS + h] = ps;
    }
    __syncthreads();

    // ---- phase B: per-(d,h) softmax, store UNNORMALIZED count-weighted exp
    if (t < NF * HEADS) {
        int d = t >> 2, h = t & 3;
        float edv = edL[d * HEADS + h];
        float mx = -INFINITY;
        #pragma unroll
        for (int s = 0; s < NF; ++s) {
            if (cntL[d * NF + s]) {
                float lg = esL[s * HEADS + h] + edv;
                lg = fmaxf(lg, 0.2f * lg);
                mx = fmaxf(mx, lg);
            }
        }
        float sum = 0.f;
        #pragma unroll
        for (int s = 0; s < NF; ++s) {
            int c = cntL[d * NF + s];
            float a = 0.f;
            if (c) {
                float lg = esL[s * HEADS + h] + edv;
                lg = fmaxf(lg, 0.2f * lg);
                a = (float)c * __expf(lg - mx);
                sum += a;
            }
            aBf[h * ALS_H + d * ALS_D + s] = f2bf(a);
        }
        rsumL[h * NF + d] = 1.0f / sum;
    }
    __syncthreads();

    // ---- phase C: aggregate (dg = t>>6 rows d = 8dg..; cg = t&63 cols 8cg..)
    int dg = t >> 6, cg = t & 63, c0 = cg * 8, h = cg >> 4;
    const unsigned short* aB = &aBf[h * ALS_H];
    float acc[8][8];
    #pragma unroll
    for (int dd = 0; dd < 8; ++dd)
        #pragma unroll
        for (int j = 0; j < 8; ++j) acc[dd][j] = 0.f;

    for (int s = 0; s < NF; ++s) {
        u16x8 u = *(const u16x8*)&h1[(size_t)(nb + s) * H1DIM + c0];
        float hv[8];
        #pragma unroll
        for (int j = 0; j < 8; ++j) hv[j] = bf2f((unsigned short)u[j]);
        #pragma unroll
        for (int dd = 0; dd < 8; ++dd) {
            float a = bf2f(aB[(dg * 8 + dd) * ALS_D + s]);
            #pragma unroll
            for (int j = 0; j < 8; ++j) acc[dd][j] = fmaf(a, hv[j], acc[dd][j]);
        }
    }
    #pragma unroll
    for (int dd = 0; dd < 8; ++dd) {
        int d = dg * 8 + dd;
        float rs = rsumL[h * NF + d];
        u16x8 o;
        #pragma unroll
        for (int j = 0; j < 8; ++j) {
            float v = acc[dd][j] * rs + b1[c0 + j];
            v = (v > 0.f) ? v : expm1f(v);
            o[j] = (short)f2bf(v);
        }
        *(u16x8*)&x1[(size_t)(nb + d) * H1DIM + c0] = o;
    }
}

// ---------------------------------------------------------------------------
// fused GAT2: stage h2 + in-block logits + softmax + collapsed mean-pool
// block 128 thr, one graph
// ---------------------------------------------------------------------------
__global__ __launch_bounds__(128) void k_gat2f(
    const float* __restrict__ h2, const float* __restrict__ as2,
    const float* __restrict__ ad2, const int* __restrict__ cnt,
    const float* __restrict__ b2, const float* __restrict__ gl,
    float* __restrict__ dout)
{
    int b = blockIdx.x, t = threadIdx.x, nb = b * NF;
    __shared__ float h2s[NF * 132];
    __shared__ float esL[NF], edL[NF], wLn[NF];
    __shared__ unsigned short cntL[NF * NF];
    __shared__ float alphaL[NF * ALS_D];

    for (int i = t; i < NF * NF; i += 128)
        cntL[i] = (unsigned short)cnt[b * NF * NF + i];
    for (int i = t; i < NF * HID / 4; i += 128) {
        int r = i >> 5, c4 = (i & 31) * 4;
        *(float4*)&h2s[r * 132 + c4] = *(const float4*)&h2[(size_t)(nb + r) * HID + c4];
    }
    __syncthreads();

    // logits: (n = t>>2, sd = (t>>1)&1, half = t&1)
    {
        int n = t >> 2, sd = (t >> 1) & 1, hf = t & 1;
        const float* att = sd ? ad2 : as2;
        float p = 0.f;
        #pragma unroll
        for (int j = 0; j < 64; ++j)
            p = fmaf(h2s[n * 132 + hf * 64 + j], att[hf * 64 + j], p);
        p += __shfl_xor(p, 1);
        if (!hf) { if (sd) edL[n] = p; else esL[n] = p; }
    }
    __syncthreads();

    if (t < NF) {
        int d = t;
        float edv = edL[d];
        float mx = -INFINITY;
        #pragma unroll
        for (int s = 0; s < NF; ++s) {
            if (cntL[d * NF + s]) {
                float lg = esL[s] + edv;
                lg = fmaxf(lg, 0.2f * lg);
                mx = fmaxf(mx, lg);
            }
        }
        float sum = 0.f;
        #pragma unroll
        for (int s = 0; s < NF; ++s) {
            int c = cntL[d * NF + s];
            float a = 0.f;
            if (c) {
                float lg = esL[s] + edv;
                lg = fmaxf(lg, 0.2f * lg);
                a = (float)c * __expf(lg - mx);
                sum += a;
            }
            alphaL[d * ALS_D + s] = a;
        }
        float rs = 1.0f / sum;
        #pragma unroll
        for (int s = 0; s < NF; ++s) alphaL[d * ALS_D + s] *= rs;
    }
    __syncthreads();
    if (t < NF) {
        float a = 0.f;
        #pragma unroll
        for (int d = 0; d < NF; ++d) a += alphaL[d * ALS_D + t];
        wLn[t] = a;
    }
    __syncthreads();

    float acc = 0.f;
    #pragma unroll 8
    for (int s = 0; s < NF; ++s) acc = fmaf(wLn[s], h2s[s * 132 + t], acc);
    dout[(size_t)b * HID + t] = acc * (1.0f / NF) + b2[t];
    if (b == 0 && t < NF)
        dout[(size_t)NB * HID + t] = 1.0f / (1.0f + __expf(-gl[t]));
}

// ---------------------------------------------------------------------------
extern "C" void kernel_launch(void* const* d_in, const int* in_sizes, int n_in,
                              void* d_out, int out_size, void* d_ws, size_t ws_size,
                              hipStream_t stream)
{
    const float* xf    = (const float*)d_in[0];
    const float* Wa    = (const float*)d_in[1];
    const float* ba    = (const float*)d_in[2];
    const float* gamma = (const float*)d_in[3];
    const float* beta  = (const float*)d_in[4];
    const float* gl    = (const float*)d_in[5];
    const float* w1    = (const float*)d_in[6];
    const float* as1   = (const float*)d_in[7];
    const float* ad1   = (const float*)d_in[8];
    const float* b1    = (const float*)d_in[9];
    const float* w2    = (const float*)d_in[10];
    const float* as2   = (const float*)d_in[11];
    const float* ad2   = (const float*)d_in[12];
    const float* b2    = (const float*)d_in[13];
    const int*   eidx  = (const int*)d_in[14];
    const int*   bidx  = (const int*)d_in[15];
    const int E = in_sizes[14] / 2;
    const int* srcG = eidx;
    const int* dstG = eidx + E;

    char* w = (char*)d_ws;
    unsigned short* x0b = (unsigned short*)w; w += (size_t)NTOT * HID * 2;     // 8 MB
    unsigned short* h1b = (unsigned short*)w; w += (size_t)NTOT * H1DIM * 2;   // 32 MB
    unsigned short* x1b = (unsigned short*)w; w += (size_t)NTOT * H1DIM * 2;   // 32 MB
    float* h2           = (float*)w;          w += (size_t)NTOT * HID * 4;     // 16 MB
    unsigned short* w1T = (unsigned short*)w; w += (size_t)H1DIM * HID * 2;
    unsigned short* w2T = (unsigned short*)w; w += (size_t)HID * H1DIM * 2;
    unsigned short* WaT = (unsigned short*)w; w += (size_t)HID * DIN * 2;
    int*   cnt          = (int*)w;            w += (size_t)NB * NF * NF * 4;   // 4 MB

    hipMemsetAsync(cnt, 0, (size_t)NB * NF * NF * 4, stream);

    k_prep<<<(2 * HID * H1DIM + DIN * HID) / 256, 256, 0, stream>>>(
        w1, w2, Wa, w1T, w2T, WaT);
    k_align<<<NTOT / 32, 256, 0, stream>>>(xf, WaT, ba, gamma, beta, gl, x0b);
    k_cnt<<<(E + 255) / 256, 256, 0, stream>>>(srcG, dstG, bidx, E, cnt);

    // h1 = x0 @ w1 : [32768,128] @ [128,512] (bf16 MFMA)
    mfma_gemm_bt<128, 4, 1><<<dim3(H1DIM / 128, NTOT / 128), 256, 0, stream>>>(
        x0b, w1T, h1b, NTOT, H1DIM, HID);

    k_gat1f<<<NB, 256, 0, stream>>>(h1b, as1, ad1, cnt, b1, x1b);

    // h2 = x1 @ w2 : [32768,512] @ [512,128] (bf16 MFMA, fp32 out)
    mfma_gemm_bt<64, 2, 0><<<dim3(HID / 128, NTOT / 64), 256, 0, stream>>>(
        x1b, w2T, h2, NTOT, HID, H1DIM);

    k_gat2f<<<NB, 128, 0, stream>>>(h2, as2, ad2, cnt, b2, gl, (float*)d_out);
}

// Round 5
// 165.519 us; speedup vs baseline: 3.1082x; 1.3007x over previous
//
#include <hip/hip_runtime.h>
#include <hip/hip_bf16.h>
#include <cstdint>
#include <cstddef>

#define NB    1024          // batch (graphs)
#define NF    32            // fields per graph
#define DIN   64
#define HID   128
#define HEADS 4
#define NTOT  (NB*NF)       // 32768 nodes
#define H1DIM (HEADS*HID)   // 512

typedef __attribute__((ext_vector_type(8))) short          bf16x8;
typedef __attribute__((ext_vector_type(8))) unsigned short u16x8;
typedef __attribute__((ext_vector_type(4))) float          f32x4;

__device__ __forceinline__ float bf2f(unsigned short u) {
    return __uint_as_float(((unsigned)u) << 16);
}
__device__ __forceinline__ unsigned short f2bf(float f) {
    unsigned u = __float_as_uint(f);
    return (unsigned short)((u + 0x7FFF + ((u >> 16) & 1)) >> 16);   // RNE
}

// ---------------------------------------------------------------------------
// weight prep: w1T[512][128], w2T[128][512], WaT[128][64]  (all bf16, B^T)
// ---------------------------------------------------------------------------
__global__ __launch_bounds__(256) void k_prep(
    const float* __restrict__ w1, const float* __restrict__ w2,
    const float* __restrict__ Wa,
    unsigned short* __restrict__ w1T, unsigned short* __restrict__ w2T,
    unsigned short* __restrict__ WaT)
{
    int i = blockIdx.x * 256 + threadIdx.x;
    if (i < HID * H1DIM) {                   // w1T[n][k] = w1[k][n]
        int n = i >> 7, k = i & 127;
        w1T[i] = f2bf(w1[k * H1DIM + n]);
    } else if (i < 2 * HID * H1DIM) {        // w2T[n][k] = w2[k][n]
        int j = i - HID * H1DIM;
        int n = j >> 9, k = j & 511;
        w2T[j] = f2bf(w2[k * HID + n]);
    } else {                                 // WaT[c][k] = Wa[k][c]
        int j = i - 2 * HID * H1DIM;
        int c = j >> 6, k = j & 63;
        WaT[j] = f2bf(Wa[k * HID + c]);
    }
}

// ---------------------------------------------------------------------------
// MEGA kernel: one block = one graph (32 nodes). 256 thr = 4 waves.
// Phases: cnt build | aligner GEMM+LN+gate | GEMM1 (+in-reg logits, h1T->LDS)
//         | softmax1 | PV1 via MFMA (+ELU -> x1 LDS) | GEMM2 (+logits2)
//         | softmax2 | collapsed mean-pool -> dout
// LDS strides are 8*odd u16 => 16B-aligned rows, <=2-way bank conflicts.
// ---------------------------------------------------------------------------
__global__ __launch_bounds__(256, 2) void k_mega(
    const float* __restrict__ xf, const unsigned short* __restrict__ WaT,
    const float* __restrict__ ba, const float* __restrict__ gamma,
    const float* __restrict__ beta, const float* __restrict__ gl,
    const unsigned short* __restrict__ w1T, const float* __restrict__ as1,
    const float* __restrict__ ad1, const float* __restrict__ b1,
    const unsigned short* __restrict__ w2T, const float* __restrict__ as2,
    const float* __restrict__ ad2, const float* __restrict__ b2,
    const int* __restrict__ src, const int* __restrict__ dst, int epg,
    float* __restrict__ dout)
{
    __shared__ char S[72192];
    unsigned short* h1T    = (unsigned short*)S;             // [512][40]  40960B
    unsigned short* x1L    = (unsigned short*)S;             // [32][520]  33280B (alias, after barrier)
    unsigned short* alphaL = (unsigned short*)(S + 40960);   // [128][40]  10240B
    unsigned short* x0L    = (unsigned short*)(S + 51200);   // [32][136]   8704B
    int*   cntL  = (int*)  (S + 59904);                      // [1024]      4096B
    float* lnS   = (float*)(S + 64000);                      // [4][32]
    float* lnS2  = (float*)(S + 64512);
    float* esL   = (float*)(S + 65024);                      // [4*32]
    float* edL   = (float*)(S + 65536);
    float* rsumL = (float*)(S + 66048);                      // [128]
    float* es2p  = (float*)(S + 66560);                      // [4][32]
    float* ed2p  = (float*)(S + 67072);
    float* aL2   = (float*)(S + 67584);                      // [32][33] f32
    float* sc2   = (float*)(S + 71808);                      // es2L[32] ed2L[32] wn2[32]

    const int b = blockIdx.x, t = threadIdx.x;
    const int l = t & 63, w = t >> 6;
    const int g = l >> 4, i16 = l & 15;
    const int nb = b * NF;
    const f32x4 zf4 = {0.f, 0.f, 0.f, 0.f};

    // ---------------- P0: per-graph edge count matrix (LDS atomics) --------
    for (int i = t; i < NF * NF; i += 256) cntL[i] = 0;
    __syncthreads();
    for (int i = t; i < epg; i += 256) {
        int sv = src[b * epg + i] - nb;
        int dv = dst[b * epg + i] - nb;
        atomicAdd(&cntL[dv * NF + sv], 1);
    }
    if (t < NF) atomicAdd(&cntL[t * NF + t], 1);   // self-loops

    // ---------------- P1: aligner GEMM (32x128, K=64) + bias + LN + gate ---
    f32x4 accA[2][2];
    #pragma unroll
    for (int m = 0; m < 2; ++m)
        #pragma unroll
        for (int n = 0; n < 2; ++n) accA[m][n] = zf4;

    #pragma unroll
    for (int k = 0; k < 2; ++k) {                 // k0 = k*32
        bf16x8 aF[2];
        #pragma unroll
        for (int m = 0; m < 2; ++m) {
            const float* p = &xf[(size_t)(nb + m * 16 + i16) * DIN + k * 32 + g * 8];
            float4 f0 = *(const float4*)p;
            float4 f1 = *(const float4*)(p + 4);
            u16x8 v;
            v[0] = f2bf(f0.x); v[1] = f2bf(f0.y); v[2] = f2bf(f0.z); v[3] = f2bf(f0.w);
            v[4] = f2bf(f1.x); v[5] = f2bf(f1.y); v[6] = f2bf(f1.z); v[7] = f2bf(f1.w);
            aF[m] = (bf16x8)v;
        }
        #pragma unroll
        for (int n = 0; n < 2; ++n) {
            bf16x8 bF = *(const bf16x8*)&WaT[(size_t)(w * 32 + n * 16 + i16) * DIN + k * 32 + g * 8];
            #pragma unroll
            for (int m = 0; m < 2; ++m)
                accA[m][n] = __builtin_amdgcn_mfma_f32_16x16x32_bf16(aF[m], bF, accA[m][n], 0, 0, 0);
        }
    }
    // bias + LN partial sums (this wave covers cols w*32 .. w*32+31)
    float val[2][2][4];
    float bav[2];
    #pragma unroll
    for (int n = 0; n < 2; ++n) bav[n] = ba[w * 32 + n * 16 + i16];
    float ps[2][4], ps2[2][4];
    #pragma unroll
    for (int m = 0; m < 2; ++m)
        #pragma unroll
        for (int v = 0; v < 4; ++v) {
            float a0 = accA[m][0][v] + bav[0];
            float a1 = accA[m][1][v] + bav[1];
            val[m][0][v] = a0; val[m][1][v] = a1;
            ps[m][v] = a0 + a1;
            ps2[m][v] = a0 * a0 + a1 * a1;
        }
    #pragma unroll
    for (int o = 1; o < 16; o <<= 1) {
        #pragma unroll
        for (int m = 0; m < 2; ++m)
            #pragma unroll
            for (int v = 0; v < 4; ++v) {
                ps[m][v]  += __shfl_xor(ps[m][v], o);
                ps2[m][v] += __shfl_xor(ps2[m][v], o);
            }
    }
    if (i16 == 0) {
        #pragma unroll
        for (int m = 0; m < 2; ++m)
            #pragma unroll
            for (int v = 0; v < 4; ++v) {
                int r = m * 16 + g * 4 + v;
                lnS[w * 32 + r]  = ps[m][v];
                lnS2[w * 32 + r] = ps2[m][v];
            }
    }
    __syncthreads();
    // LN finish + gate -> x0L bf16
    #pragma unroll
    for (int m = 0; m < 2; ++m)
        #pragma unroll
        for (int v = 0; v < 4; ++v) {
            int r = m * 16 + g * 4 + v;
            float S1 = lnS[r] + lnS[32 + r] + lnS[64 + r] + lnS[96 + r];
            float S2 = lnS2[r] + lnS2[32 + r] + lnS2[64 + r] + lnS2[96 + r];
            float mu = S1 * (1.0f / HID);
            float var = S2 * (1.0f / HID) - mu * mu;
            float rs = rsqrtf(var + 1e-5f);
            float gt = 1.0f / (1.0f + __expf(-gl[r]));
            #pragma unroll
            for (int n = 0; n < 2; ++n) {
                int c = w * 32 + n * 16 + i16;
                float xv = ((val[m][n][v] - mu) * rs * gamma[c] + beta[c]) * gt;
                x0L[r * 136 + c] = f2bf(xv);
            }
        }
    __syncthreads();

    // ---------------- P2: GEMM1 (32 x 512, K=128); wave w -> cols w*128.. --
    f32x4 acc1[2][8];
    #pragma unroll
    for (int m = 0; m < 2; ++m)
        #pragma unroll
        for (int n = 0; n < 8; ++n) acc1[m][n] = zf4;

    #pragma unroll 1
    for (int k = 0; k < 4; ++k) {
        bf16x8 aF[2];
        #pragma unroll
        for (int m = 0; m < 2; ++m)
            aF[m] = *(const bf16x8*)&x0L[(m * 16 + i16) * 136 + k * 32 + g * 8];
        #pragma unroll
        for (int n = 0; n < 8; ++n) {
            bf16x8 bF = *(const bf16x8*)&w1T[(size_t)(w * 128 + n * 16 + i16) * 128 + k * 32 + g * 8];
            #pragma unroll
            for (int m = 0; m < 2; ++m)
                acc1[m][n] = __builtin_amdgcn_mfma_f32_16x16x32_bf16(aF[m], bF, acc1[m][n], 0, 0, 0);
        }
    }
    // in-register logits for head w (fp32 accs), + h1T (transposed) store
    {
        float asv[8], adv[8];
        #pragma unroll
        for (int n = 0; n < 8; ++n) {
            int f = n * 16 + i16;
            asv[n] = as1[w * 128 + f];
            adv[n] = ad1[w * 128 + f];
        }
        float pe[2][4], pd[2][4];
        #pragma unroll
        for (int m = 0; m < 2; ++m)
            #pragma unroll
            for (int v = 0; v < 4; ++v) {
                float e = 0.f, d = 0.f;
                #pragma unroll
                for (int n = 0; n < 8; ++n) {
                    e = fmaf(acc1[m][n][v], asv[n], e);
                    d = fmaf(acc1[m][n][v], adv[n], d);
                }
                pe[m][v] = e; pd[m][v] = d;
            }
        #pragma unroll
        for (int o = 1; o < 16; o <<= 1) {
            #pragma unroll
            for (int m = 0; m < 2; ++m)
                #pragma unroll
                for (int v = 0; v < 4; ++v) {
                    pe[m][v] += __shfl_xor(pe[m][v], o);
                    pd[m][v] += __shfl_xor(pd[m][v], o);
                }
        }
        if (i16 == 0) {
            #pragma unroll
            for (int m = 0; m < 2; ++m)
                #pragma unroll
                for (int v = 0; v < 4; ++v) {
                    int r = m * 16 + g * 4 + v;
                    esL[w * 32 + r] = pe[m][v];
                    edL[w * 32 + r] = pd[m][v];
                }
        }
        #pragma unroll
        for (int m = 0; m < 2; ++m)
            #pragma unroll
            for (int n = 0; n < 8; ++n) {
                int c = w * 128 + n * 16 + i16;
                unsigned d0 = (unsigned)f2bf(acc1[m][n][0]) | ((unsigned)f2bf(acc1[m][n][1]) << 16);
                unsigned d1 = (unsigned)f2bf(acc1[m][n][2]) | ((unsigned)f2bf(acc1[m][n][3]) << 16);
                uint2 pk = {d0, d1};
                *(uint2*)&h1T[c * 40 + m * 16 + g * 4] = pk;   // h1T[c][row..row+3]
            }
    }
    __syncthreads();

    // ---------------- P3: softmax layer 1 (128 threads: (d,h)) -------------
    if (t < 128) {
        int d = t >> 2, h = t & 3;
        float edv = edL[h * 32 + d];
        float mx = -INFINITY;
        #pragma unroll
        for (int s = 0; s < NF; ++s) {
            if (cntL[d * NF + s]) {
                float lg = esL[h * 32 + s] + edv;
                lg = fmaxf(lg, 0.2f * lg);
                mx = fmaxf(mx, lg);
            }
        }
        float sum = 0.f;
        #pragma unroll
        for (int s = 0; s < NF; ++s) {
            int c = cntL[d * NF + s];
            float a = 0.f;
            if (c) {
                float lg = esL[h * 32 + s] + edv;
                lg = fmaxf(lg, 0.2f * lg);
                a = (float)c * __expf(lg - mx);
                sum += a;
            }
            alphaL[(h * 32 + d) * 40 + s] = f2bf(a);
        }
        rsumL[h * 32 + d] = 1.0f / sum;
    }
    __syncthreads();

    // ---------------- P4: PV1 = alpha(32x32) @ h1(32x512) via MFMA ---------
    f32x4 po[2][8];
    {
        bf16x8 aF2[2];
        #pragma unroll
        for (int m = 0; m < 2; ++m)
            aF2[m] = *(const bf16x8*)&alphaL[(w * 32 + m * 16 + i16) * 40 + g * 8];
        #pragma unroll
        for (int n = 0; n < 8; ++n) {
            bf16x8 bF = *(const bf16x8*)&h1T[(w * 128 + n * 16 + i16) * 40 + g * 8];
            #pragma unroll
            for (int m = 0; m < 2; ++m)
                po[m][n] = __builtin_amdgcn_mfma_f32_16x16x32_bf16(aF2[m], bF, zf4, 0, 0, 0);
        }
    }
    __syncthreads();          // all h1T reads done; x1L may now overwrite it
    // epilogue: /sum, +b1, ELU -> x1L (bf16)
    #pragma unroll
    for (int m = 0; m < 2; ++m)
        #pragma unroll
        for (int n = 0; n < 8; ++n) {
            int c = w * 128 + n * 16 + i16;
            float bias = b1[c];
            #pragma unroll
            for (int v = 0; v < 4; ++v) {
                int r = m * 16 + g * 4 + v;
                float x = po[m][n][v] * rsumL[w * 32 + r] + bias;
                x = (x > 0.f) ? x : expm1f(x);
                x1L[r * 520 + c] = f2bf(x);
            }
        }
    __syncthreads();

    // ---------------- P5: GEMM2 (32 x 128, K=512); wave w -> cols w*32.. ---
    f32x4 acc2[2][2];
    #pragma unroll
    for (int m = 0; m < 2; ++m)
        #pragma unroll
        for (int n = 0; n < 2; ++n) acc2[m][n] = zf4;

    #pragma unroll 1
    for (int k = 0; k < 16; ++k) {
        bf16x8 aF[2];
        #pragma unroll
        for (int m = 0; m < 2; ++m)
            aF[m] = *(const bf16x8*)&x1L[(m * 16 + i16) * 520 + k * 32 + g * 8];
        #pragma unroll
        for (int n = 0; n < 2; ++n) {
            bf16x8 bF = *(const bf16x8*)&w2T[(size_t)(w * 32 + n * 16 + i16) * 512 + k * 32 + g * 8];
            #pragma unroll
            for (int m = 0; m < 2; ++m)
                acc2[m][n] = __builtin_amdgcn_mfma_f32_16x16x32_bf16(aF[m], bF, acc2[m][n], 0, 0, 0);
        }
    }
    // logits2 partials (cols w*32..w*32+31)
    {
        float a2v[2], d2v[2];
        #pragma unroll
        for (int n = 0; n < 2; ++n) {
            int c = w * 32 + n * 16 + i16;
            a2v[n] = as2[c]; d2v[n] = ad2[c];
        }
        float pe[2][4], pd[2][4];
        #pragma unroll
        for (int m = 0; m < 2; ++m)
            #pragma unroll
            for (int v = 0; v < 4; ++v) {
                float e = 0.f, d = 0.f;
                #pragma unroll
                for (int n = 0; n < 2; ++n) {
                    e = fmaf(acc2[m][n][v], a2v[n], e);
                    d = fmaf(acc2[m][n][v], d2v[n], d);
                }
                pe[m][v] = e; pd[m][v] = d;
            }
        #pragma unroll
        for (int o = 1; o < 16; o <<= 1) {
            #pragma unroll
            for (int m = 0; m < 2; ++m)
                #pragma unroll
                for (int v = 0; v < 4; ++v) {
                    pe[m][v] += __shfl_xor(pe[m][v], o);
                    pd[m][v] += __shfl_xor(pd[m][v], o);
                }
        }
        if (i16 == 0) {
            #pragma unroll
            for (int m = 0; m < 2; ++m)
                #pragma unroll
                for (int v = 0; v < 4; ++v) {
                    int r = m * 16 + g * 4 + v;
                    es2p[w * 32 + r] = pe[m][v];
                    ed2p[w * 32 + r] = pd[m][v];
                }
        }
    }
    __syncthreads();

    // ---------------- P6: softmax layer 2 + column weights -----------------
    float* es2L = sc2;
    float* ed2L = sc2 + 32;
    float* wn2  = sc2 + 64;
    if (t < NF) {
        es2L[t] = es2p[t] + es2p[32 + t] + es2p[64 + t] + es2p[96 + t];
        ed2L[t] = ed2p[t] + ed2p[32 + t] + ed2p[64 + t] + ed2p[96 + t];
    }
    __syncthreads();
    if (t < NF) {
        int d = t;
        float edv = ed2L[d];
        float mx = -INFINITY;
        #pragma unroll
        for (int s = 0; s < NF; ++s) {
            if (cntL[d * NF + s]) {
                float lg = es2L[s] + edv;
                lg = fmaxf(lg, 0.2f * lg);
                mx = fmaxf(mx, lg);
            }
        }
        float sum = 0.f;
        #pragma unroll
        for (int s = 0; s < NF; ++s) {
            int c = cntL[d * NF + s];
            float a = 0.f;
            if (c) {
                float lg = es2L[s] + edv;
                lg = fmaxf(lg, 0.2f * lg);
                a = (float)c * __expf(lg - mx);
                sum += a;
            }
            aL2[d * 33 + s] = a;
        }
        float rs = 1.0f / sum;
        #pragma unroll
        for (int s = 0; s < NF; ++s) aL2[d * 33 + s] *= rs;
    }
    __syncthreads();
    if (t < NF) {
        float a = 0.f;
        #pragma unroll
        for (int d = 0; d < NF; ++d) a += aL2[d * 33 + t];
        wn2[t] = a;
    }
    __syncthreads();

    // ---------------- P7: collapsed mean-pool from register h2 -------------
    {
        float wr_[2][4];
        #pragma unroll
        for (int m = 0; m < 2; ++m)
            #pragma unroll
            for (int v = 0; v < 4; ++v) wr_[m][v] = wn2[m * 16 + g * 4 + v];
        float pl[2];
        #pragma unroll
        for (int n = 0; n < 2; ++n) {
            float a = 0.f;
            #pragma unroll
            for (int m = 0; m < 2; ++m)
                #pragma unroll
                for (int v = 0; v < 4; ++v)
                    a = fmaf(wr_[m][v], acc2[m][n][v], a);
            pl[n] = a;
        }
        #pragma unroll
        for (int n = 0; n < 2; ++n) {
            pl[n] += __shfl_xor(pl[n], 16);
            pl[n] += __shfl_xor(pl[n], 32);
        }
        if (l < 16) {
            #pragma unroll
            for (int n = 0; n < 2; ++n) {
                int c = w * 32 + n * 16 + l;
                dout[(size_t)b * HID + c] = pl[n] * (1.0f / NF) + b2[c];
            }
        }
    }
    if (b == 0 && t < NF)
        dout[(size_t)NB * HID + t] = 1.0f / (1.0f + __expf(-gl[t]));
}

// ---------------------------------------------------------------------------
extern "C" void kernel_launch(void* const* d_in, const int* in_sizes, int n_in,
                              void* d_out, int out_size, void* d_ws, size_t ws_size,
                              hipStream_t stream)
{
    const float* xf    = (const float*)d_in[0];
    const float* Wa    = (const float*)d_in[1];
    const float* ba    = (const float*)d_in[2];
    const float* gamma = (const float*)d_in[3];
    const float* beta  = (const float*)d_in[4];
    const float* gl    = (const float*)d_in[5];
    const float* w1    = (const float*)d_in[6];
    const float* as1   = (const float*)d_in[7];
    const float* ad1   = (const float*)d_in[8];
    const float* b1    = (const float*)d_in[9];
    const float* w2    = (const float*)d_in[10];
    const float* as2   = (const float*)d_in[11];
    const float* ad2   = (const float*)d_in[12];
    const float* b2    = (const float*)d_in[13];
    const int*   eidx  = (const int*)d_in[14];
    const int E = in_sizes[14] / 2;
    const int* srcG = eidx;
    const int* dstG = eidx + E;
    const int epg = (E - NTOT) / NB;   // template edges per graph (graph-major)

    char* w = (char*)d_ws;
    unsigned short* w1T = (unsigned short*)w; w += (size_t)H1DIM * HID * 2;
    unsigned short* w2T = (unsigned short*)w; w += (size_t)HID * H1DIM * 2;
    unsigned short* WaT = (unsigned short*)w; w += (size_t)HID * DIN * 2;

    k_prep<<<(2 * HID * H1DIM + DIN * HID) / 256, 256, 0, stream>>>(
        w1, w2, Wa, w1T, w2T, WaT);

    k_mega<<<NB, 256, 0, stream>>>(
        xf, WaT, ba, gamma, beta, gl, w1T, as1, ad1, b1,
        w2T, as2, ad2, b2, srcG, dstG, epg, (float*)d_out);
}

// Round 8
// 158.801 us; speedup vs baseline: 3.2397x; 1.0423x over previous
//
#include <hip/hip_runtime.h>
#include <hip/hip_bf16.h>
#include <cstdint>
#include <cstddef>

#define NB    1024          // batch (graphs)
#define NF    32            // fields per graph
#define DIN   64
#define HID   128
#define HEADS 4
#define NTOT  (NB*NF)       // 32768 nodes
#define H1DIM (HEADS*HID)   // 512

typedef __attribute__((ext_vector_type(8))) short          bf16x8;
typedef __attribute__((ext_vector_type(8))) unsigned short u16x8;
typedef __attribute__((ext_vector_type(4))) float          f32x4;

__device__ __forceinline__ float bf2f(unsigned short u) {
    return __uint_as_float(((unsigned)u) << 16);
}
__device__ __forceinline__ unsigned short f2bf(float f) {
    unsigned u = __float_as_uint(f);
    return (unsigned short)((u + 0x7FFF + ((u >> 16) & 1)) >> 16);   // RNE
}

// ---- swizzled LDS index helpers (u16-element index; 16B-chunk XOR) --------
// x0L [32][128]  : key = row&7     (read rows are m*16+i16 -> key=i16&7, 8 slots)
__device__ __forceinline__ int x0_at(int r, int c) {
    return r * 128 + ((((c >> 3) ^ (r & 7)) & 15) << 3) + (c & 7);
}
// h1T [512][32]  : key = (row>>1)&3  (read rows f=..+i16; with row&1 parity -> 8 slots)
__device__ __forceinline__ int h1_at(int f, int s) {
    return f * 32 + ((((s >> 3) ^ ((f >> 1) & 3)) & 3) << 3) + (s & 7);
}
// x1L [32][512]  : key = (row>>1)&7  (read rows m*16+i16 -> key=(i16>>1)&7, 8 slots)
__device__ __forceinline__ int x1_at(int r, int c) {
    return r * 512 + ((((c >> 3) ^ ((r >> 1) & 7)) & 63) << 3) + (c & 7);
}
// alphaL [128][32]: key = (row>>1)&3
__device__ __forceinline__ int al_at(int rr, int s) {
    return rr * 32 + ((((s >> 3) ^ ((rr >> 1) & 3)) & 3) << 3) + (s & 7);
}

// ---------------------------------------------------------------------------
// weight prep: w1T[512][128], w2T[128][512], WaT[128][64]  (all bf16, B^T)
// ---------------------------------------------------------------------------
__global__ __launch_bounds__(256) void k_prep(
    const float* __restrict__ w1, const float* __restrict__ w2,
    const float* __restrict__ Wa,
    unsigned short* __restrict__ w1T, unsigned short* __restrict__ w2T,
    unsigned short* __restrict__ WaT)
{
    int i = blockIdx.x * 256 + threadIdx.x;
    if (i < HID * H1DIM) {                   // w1T[n][k] = w1[k][n]
        int n = i >> 7, k = i & 127;
        w1T[i] = f2bf(w1[k * H1DIM + n]);
    } else if (i < 2 * HID * H1DIM) {        // w2T[n][k] = w2[k][n]
        int j = i - HID * H1DIM;
        int n = j >> 9, k = j & 511;
        w2T[j] = f2bf(w2[k * HID + n]);
    } else {                                 // WaT[c][k] = Wa[k][c]
        int j = i - 2 * HID * H1DIM;
        int c = j >> 6, k = j & 63;
        WaT[j] = f2bf(Wa[k * HID + c]);
    }
}

// ---------------------------------------------------------------------------
// MEGA kernel: one block = one graph. 256 thr = 4 waves.
// LDS plan (54144 B -> 3 blocks/CU):
//   U [0,32768)    : cntI int[1024] (P0) -> h1T u16[512][32] (P2-P4)
//                    -> x1L u16[32][512] (P4e-P5)
//   A [32768,40960): alphaL u16[128][32]
//   X [40960,49152): x0L u16[32][128] (P1-P2) -> aL2 f32[32][33] (P6)
//   C [49152,50176): cntB u8[1024]
//   S [50176,54144): lnS,lnS2,esL,edL,rsumL,es2p,ed2p f32[128] ea + sc2[96]
// ---------------------------------------------------------------------------
__global__ __launch_bounds__(256, 3) void k_mega(
    const float* __restrict__ xf, const unsigned short* __restrict__ WaT,
    const float* __restrict__ ba, const float* __restrict__ gamma,
    const float* __restrict__ beta, const float* __restrict__ gl,
    const unsigned short* __restrict__ w1T, const float* __restrict__ as1,
    const float* __restrict__ ad1, const float* __restrict__ b1,
    const unsigned short* __restrict__ w2T, const float* __restrict__ as2,
    const float* __restrict__ ad2, const float* __restrict__ b2,
    const int* __restrict__ src, const int* __restrict__ dst, int epg,
    float* __restrict__ dout)
{
    __shared__ __align__(16) char S[54144];
    int*            cntI   = (int*)S;
    unsigned short* h1T    = (unsigned short*)S;
    unsigned short* x1L    = (unsigned short*)S;
    unsigned short* alphaL = (unsigned short*)(S + 32768);
    unsigned short* x0L    = (unsigned short*)(S + 40960);
    float*          aL2    = (float*)(S + 40960);            // [32][33]
    unsigned char*  cntB   = (unsigned char*)(S + 49152);
    float* lnS   = (float*)(S + 50176);
    float* lnS2  = (float*)(S + 50688);
    float* esL   = (float*)(S + 51200);
    float* edL   = (float*)(S + 51712);
    float* rsumL = (float*)(S + 52224);
    float* es2p  = (float*)(S + 52736);
    float* ed2p  = (float*)(S + 53248);
    float* sc2   = (float*)(S + 53760);                      // es2L|ed2L|wn2

    const int b = blockIdx.x, t = threadIdx.x;
    const int l = t & 63, w = t >> 6;
    const int g = l >> 4, i16 = l & 15;
    const int nb = b * NF;
    const f32x4 zf4 = {0.f, 0.f, 0.f, 0.f};

    // ---------------- P0: per-graph edge count matrix ----------------------
    for (int i = t; i < NF * NF; i += 256) cntI[i] = 0;
    __syncthreads();
    for (int i = t; i < epg; i += 256) {
        int sv = src[b * epg + i] - nb;
        int dv = dst[b * epg + i] - nb;
        atomicAdd(&cntI[dv * NF + sv], 1);
    }
    if (t < NF) atomicAdd(&cntI[t * NF + t], 1);   // self-loops
    __syncthreads();
    for (int i = t; i < NF * NF; i += 256) {
        int c = cntI[i];
        cntB[i] = (unsigned char)(c > 255 ? 255 : c);
    }
    __syncthreads();                                // cntI dead; U free for h1T

    // ---------------- P1: aligner GEMM (32x128, K=64) + bias + LN + gate ---
    f32x4 accA[2][2];
    #pragma unroll
    for (int m = 0; m < 2; ++m)
        #pragma unroll
        for (int n = 0; n < 2; ++n) accA[m][n] = zf4;

    #pragma unroll
    for (int k = 0; k < 2; ++k) {
        bf16x8 aF[2];
        #pragma unroll
        for (int m = 0; m < 2; ++m) {
            const float* p = &xf[(size_t)(nb + m * 16 + i16) * DIN + k * 32 + g * 8];
            float4 f0 = *(const float4*)p;
            float4 f1 = *(const float4*)(p + 4);
            u16x8 v;
            v[0] = f2bf(f0.x); v[1] = f2bf(f0.y); v[2] = f2bf(f0.z); v[3] = f2bf(f0.w);
            v[4] = f2bf(f1.x); v[5] = f2bf(f1.y); v[6] = f2bf(f1.z); v[7] = f2bf(f1.w);
            aF[m] = (bf16x8)v;
        }
        #pragma unroll
        for (int n = 0; n < 2; ++n) {
            bf16x8 bF = *(const bf16x8*)&WaT[(size_t)(w * 32 + n * 16 + i16) * DIN + k * 32 + g * 8];
            #pragma unroll
            for (int m = 0; m < 2; ++m)
                accA[m][n] = __builtin_amdgcn_mfma_f32_16x16x32_bf16(aF[m], bF, accA[m][n], 0, 0, 0);
        }
    }
    float val[2][2][4];
    float bav[2];
    #pragma unroll
    for (int n = 0; n < 2; ++n) bav[n] = ba[w * 32 + n * 16 + i16];
    float ps[2][4], ps2[2][4];
    #pragma unroll
    for (int m = 0; m < 2; ++m)
        #pragma unroll
        for (int v = 0; v < 4; ++v) {
            float a0 = accA[m][0][v] + bav[0];
            float a1 = accA[m][1][v] + bav[1];
            val[m][0][v] = a0; val[m][1][v] = a1;
            ps[m][v] = a0 + a1;
            ps2[m][v] = a0 * a0 + a1 * a1;
        }
    #pragma unroll
    for (int o = 1; o < 16; o <<= 1) {
        #pragma unroll
        for (int m = 0; m < 2; ++m)
            #pragma unroll
            for (int v = 0; v < 4; ++v) {
                ps[m][v]  += __shfl_xor(ps[m][v], o);
                ps2[m][v] += __shfl_xor(ps2[m][v], o);
            }
    }
    if (i16 == 0) {
        #pragma unroll
        for (int m = 0; m < 2; ++m)
            #pragma unroll
            for (int v = 0; v < 4; ++v) {
                int r = m * 16 + g * 4 + v;
                lnS[w * 32 + r]  = ps[m][v];
                lnS2[w * 32 + r] = ps2[m][v];
            }
    }
    __syncthreads();
    #pragma unroll
    for (int m = 0; m < 2; ++m)
        #pragma unroll
        for (int v = 0; v < 4; ++v) {
            int r = m * 16 + g * 4 + v;
            float S1 = lnS[r] + lnS[32 + r] + lnS[64 + r] + lnS[96 + r];
            float S2 = lnS2[r] + lnS2[32 + r] + lnS2[64 + r] + lnS2[96 + r];
            float mu = S1 * (1.0f / HID);
            float var = S2 * (1.0f / HID) - mu * mu;
            float rs = rsqrtf(var + 1e-5f);
            float gt = 1.0f / (1.0f + __expf(-gl[r]));
            #pragma unroll
            for (int n = 0; n < 2; ++n) {
                int c = w * 32 + n * 16 + i16;
                float xv = ((val[m][n][v] - mu) * rs * gamma[c] + beta[c]) * gt;
                x0L[x0_at(r, c)] = f2bf(xv);
            }
        }
    __syncthreads();

    // ---------------- P2: GEMM1 (32 x 512, K=128); wave w -> head w --------
    f32x4 acc1[2][8];
    #pragma unroll
    for (int m = 0; m < 2; ++m)
        #pragma unroll
        for (int n = 0; n < 8; ++n) acc1[m][n] = zf4;

    #pragma unroll 2
    for (int k = 0; k < 4; ++k) {
        bf16x8 aF[2];
        #pragma unroll
        for (int m = 0; m < 2; ++m)
            aF[m] = *(const bf16x8*)&x0L[x0_at(m * 16 + i16, k * 32 + g * 8)];
        #pragma unroll
        for (int n = 0; n < 8; ++n) {
            bf16x8 bF = *(const bf16x8*)&w1T[(size_t)(w * 128 + n * 16 + i16) * 128 + k * 32 + g * 8];
            #pragma unroll
            for (int m = 0; m < 2; ++m)
                acc1[m][n] = __builtin_amdgcn_mfma_f32_16x16x32_bf16(aF[m], bF, acc1[m][n], 0, 0, 0);
        }
    }
    // in-register logits for head w + transposed h1 store into U
    {
        float asv[8], adv[8];
        #pragma unroll
        for (int n = 0; n < 8; ++n) {
            int f = n * 16 + i16;
            asv[n] = as1[w * 128 + f];
            adv[n] = ad1[w * 128 + f];
        }
        float pe[2][4], pd[2][4];
        #pragma unroll
        for (int m = 0; m < 2; ++m)
            #pragma unroll
            for (int v = 0; v < 4; ++v) {
                float e = 0.f, d = 0.f;
                #pragma unroll
                for (int n = 0; n < 8; ++n) {
                    e = fmaf(acc1[m][n][v], asv[n], e);
                    d = fmaf(acc1[m][n][v], adv[n], d);
                }
                pe[m][v] = e; pd[m][v] = d;
            }
        #pragma unroll
        for (int o = 1; o < 16; o <<= 1) {
            #pragma unroll
            for (int m = 0; m < 2; ++m)
                #pragma unroll
                for (int v = 0; v < 4; ++v) {
                    pe[m][v] += __shfl_xor(pe[m][v], o);
                    pd[m][v] += __shfl_xor(pd[m][v], o);
                }
        }
        if (i16 == 0) {
            #pragma unroll
            for (int m = 0; m < 2; ++m)
                #pragma unroll
                for (int v = 0; v < 4; ++v) {
                    int r = m * 16 + g * 4 + v;
                    esL[w * 32 + r] = pe[m][v];
                    edL[w * 32 + r] = pd[m][v];
                }
        }
        #pragma unroll
        for (int m = 0; m < 2; ++m)
            #pragma unroll
            for (int n = 0; n < 8; ++n) {
                int f = w * 128 + n * 16 + i16;
                int s0 = m * 16 + g * 4;
                unsigned d0 = (unsigned)f2bf(acc1[m][n][0]) | ((unsigned)f2bf(acc1[m][n][1]) << 16);
                unsigned d1 = (unsigned)f2bf(acc1[m][n][2]) | ((unsigned)f2bf(acc1[m][n][3]) << 16);
                uint2 pk = {d0, d1};
                *(uint2*)&h1T[h1_at(f, s0)] = pk;
            }
    }
    __syncthreads();

    // ---------------- P3: softmax layer 1 (128 threads: (d,h)) -------------
    if (t < 128) {
        int d = t >> 2, h = t & 3;
        float edv = edL[h * 32 + d];
        float mx = -INFINITY;
        #pragma unroll
        for (int s = 0; s < NF; ++s) {
            if (cntB[d * NF + s]) {
                float lg = esL[h * 32 + s] + edv;
                lg = fmaxf(lg, 0.2f * lg);
                mx = fmaxf(mx, lg);
            }
        }
        float sum = 0.f;
        #pragma unroll
        for (int s = 0; s < NF; ++s) {
            int c = cntB[d * NF + s];
            float a = 0.f;
            if (c) {
                float lg = esL[h * 32 + s] + edv;
                lg = fmaxf(lg, 0.2f * lg);
                a = (float)c * __expf(lg - mx);
                sum += a;
            }
            alphaL[al_at(h * 32 + d, s)] = f2bf(a);
        }
        rsumL[h * 32 + d] = 1.0f / sum;
    }
    __syncthreads();

    // ---------------- P4: PV1 = alpha(32x32) @ h1(32x512) via MFMA ---------
    f32x4 po[2][8];
    {
        bf16x8 aF2[2];
        #pragma unroll
        for (int m = 0; m < 2; ++m)
            aF2[m] = *(const bf16x8*)&alphaL[al_at(w * 32 + m * 16 + i16, g * 8)];
        #pragma unroll
        for (int n = 0; n < 8; ++n) {
            bf16x8 bF = *(const bf16x8*)&h1T[h1_at(w * 128 + n * 16 + i16, g * 8)];
            #pragma unroll
            for (int m = 0; m < 2; ++m)
                po[m][n] = __builtin_amdgcn_mfma_f32_16x16x32_bf16(aF2[m], bF, zf4, 0, 0, 0);
        }
    }
    __syncthreads();          // all h1T reads done; x1L may overwrite U
    #pragma unroll
    for (int m = 0; m < 2; ++m)
        #pragma unroll
        for (int n = 0; n < 8; ++n) {
            int c = w * 128 + n * 16 + i16;
            float bias = b1[c];
            #pragma unroll
            for (int v = 0; v < 4; ++v) {
                int r = m * 16 + g * 4 + v;
                float x = po[m][n][v] * rsumL[w * 32 + r] + bias;
                x = (x > 0.f) ? x : (__expf(x) - 1.0f);
                x1L[x1_at(r, c)] = f2bf(x);
            }
        }
    __syncthreads();

    // ---------------- P5: GEMM2 (32 x 128, K=512); wave w -> cols w*32.. ---
    f32x4 acc2[2][2];
    #pragma unroll
    for (int m = 0; m < 2; ++m)
        #pragma unroll
        for (int n = 0; n < 2; ++n) acc2[m][n] = zf4;

    #pragma unroll 4
    for (int k = 0; k < 16; ++k) {
        bf16x8 aF[2];
        #pragma unroll
        for (int m = 0; m < 2; ++m)
            aF[m] = *(const bf16x8*)&x1L[x1_at(m * 16 + i16, k * 32 + g * 8)];
        #pragma unroll
        for (int n = 0; n < 2; ++n) {
            bf16x8 bF = *(const bf16x8*)&w2T[(size_t)(w * 32 + n * 16 + i16) * 512 + k * 32 + g * 8];
            #pragma unroll
            for (int m = 0; m < 2; ++m)
                acc2[m][n] = __builtin_amdgcn_mfma_f32_16x16x32_bf16(aF[m], bF, acc2[m][n], 0, 0, 0);
        }
    }
    // logits2 partials (cols w*32..w*32+31)
    {
        float a2v[2], d2v[2];
        #pragma unroll
        for (int n = 0; n < 2; ++n) {
            int c = w * 32 + n * 16 + i16;
            a2v[n] = as2[c]; d2v[n] = ad2[c];
        }
        float pe[2][4], pd[2][4];
        #pragma unroll
        for (int m = 0; m < 2; ++m)
            #pragma unroll
            for (int v = 0; v < 4; ++v) {
                float e = 0.f, d = 0.f;
                #pragma unroll
                for (int n = 0; n < 2; ++n) {
                    e = fmaf(acc2[m][n][v], a2v[n], e);
                    d = fmaf(acc2[m][n][v], d2v[n], d);
                }
                pe[m][v] = e; pd[m][v] = d;
            }
        #pragma unroll
        for (int o = 1; o < 16; o <<= 1) {
            #pragma unroll
            for (int m = 0; m < 2; ++m)
                #pragma unroll
                for (int v = 0; v < 4; ++v) {
                    pe[m][v] += __shfl_xor(pe[m][v], o);
                    pd[m][v] += __shfl_xor(pd[m][v], o);
                }
        }
        if (i16 == 0) {
            #pragma unroll
            for (int m = 0; m < 2; ++m)
                #pragma unroll
                for (int v = 0; v < 4; ++v) {
                    int r = m * 16 + g * 4 + v;
                    es2p[w * 32 + r] = pe[m][v];
                    ed2p[w * 32 + r] = pd[m][v];
                }
        }
    }
    __syncthreads();

    // ---------------- P6: softmax layer 2 + column weights -----------------
    float* es2L = sc2;
    float* ed2L = sc2 + 32;
    float* wn2  = sc2 + 64;
    if (t < NF) {
        es2L[t] = es2p[t] + es2p[32 + t] + es2p[64 + t] + es2p[96 + t];
        ed2L[t] = ed2p[t] + ed2p[32 + t] + ed2p[64 + t] + ed2p[96 + t];
    }
    __syncthreads();
    if (t < NF) {
        int d = t;
        float edv = ed2L[d];
        float mx = -INFINITY;
        #pragma unroll
        for (int s = 0; s < NF; ++s) {
            if (cntB[d * NF + s]) {
                float lg = es2L[s] + edv;
                lg = fmaxf(lg, 0.2f * lg);
                mx = fmaxf(mx, lg);
            }
        }
        float sum = 0.f;
        #pragma unroll
        for (int s = 0; s < NF; ++s) {
            int c = cntB[d * NF + s];
            float a = 0.f;
            if (c) {
                float lg = es2L[s] + edv;
                lg = fmaxf(lg, 0.2f * lg);
                a = (float)c * __expf(lg - mx);
                sum += a;
            }
            aL2[d * 33 + s] = a;
        }
        float rs = 1.0f / sum;
        #pragma unroll
        for (int s = 0; s < NF; ++s) aL2[d * 33 + s] *= rs;
    }
    __syncthreads();
    if (t < NF) {
        float a = 0.f;
        #pragma unroll
        for (int d = 0; d < NF; ++d) a += aL2[d * 33 + t];
        wn2[t] = a;
    }
    __syncthreads();

    // ---------------- P7: collapsed mean-pool from register h2 -------------
    {
        float wr_[2][4];
        #pragma unroll
        for (int m = 0; m < 2; ++m)
            #pragma unroll
            for (int v = 0; v < 4; ++v) wr_[m][v] = wn2[m * 16 + g * 4 + v];
        float pl[2];
        #pragma unroll
        for (int n = 0; n < 2; ++n) {
            float a = 0.f;
            #pragma unroll
            for (int m = 0; m < 2; ++m)
                #pragma unroll
                for (int v = 0; v < 4; ++v)
                    a = fmaf(wr_[m][v], acc2[m][n][v], a);
            pl[n] = a;
        }
        #pragma unroll
        for (int n = 0; n < 2; ++n) {
            pl[n] += __shfl_xor(pl[n], 16);
            pl[n] += __shfl_xor(pl[n], 32);
        }
        if (l < 16) {
            #pragma unroll
            for (int n = 0; n < 2; ++n) {
                int c = w * 32 + n * 16 + l;
                dout[(size_t)b * HID + c] = pl[n] * (1.0f / NF) + b2[c];
            }
        }
    }
    if (b == 0 && t < NF)
        dout[(size_t)NB * HID + t] = 1.0f / (1.0f + __expf(-gl[t]));
}

// ---------------------------------------------------------------------------
extern "C" void kernel_launch(void* const* d_in, const int* in_sizes, int n_in,
                              void* d_out, int out_size, void* d_ws, size_t ws_size,
                              hipStream_t stream)
{
    const float* xf    = (const float*)d_in[0];
    const float* Wa    = (const float*)d_in[1];
    const float* ba    = (const float*)d_in[2];
    const float* gamma = (const float*)d_in[3];
    const float* beta  = (const float*)d_in[4];
    const float* gl    = (const float*)d_in[5];
    const float* w1    = (const float*)d_in[6];
    const float* as1   = (const float*)d_in[7];
    const float* ad1   = (const float*)d_in[8];
    const float* b1    = (const float*)d_in[9];
    const float* w2    = (const float*)d_in[10];
    const float* as2   = (const float*)d_in[11];
    const float* ad2   = (const float*)d_in[12];
    const float* b2    = (const float*)d_in[13];
    const int*   eidx  = (const int*)d_in[14];
    const int E = in_sizes[14] / 2;
    const int* srcG = eidx;
    const int* dstG = eidx + E;
    const int epg = (E - NTOT) / NB;   // template edges per graph (graph-major)

    char* w = (char*)d_ws;
    unsigned short* w1T = (unsigned short*)w; w += (size_t)H1DIM * HID * 2;
    unsigned short* w2T = (unsigned short*)w; w += (size_t)HID * H1DIM * 2;
    unsigned short* WaT = (unsigned short*)w; w += (size_t)HID * DIN * 2;

    k_prep<<<(2 * HID * H1DIM + DIN * HID) / 256, 256, 0, stream>>>(
        w1, w2, Wa, w1T, w2T, WaT);

    k_mega<<<NB, 256, 0, stream>>>(
        xf, WaT, ba, gamma, beta, gl, w1T, as1, ad1, b1,
        w2T, as2, ad2, b2, srcG, dstG, epg, (float*)d_out);
}